// Round 18
// baseline (335.881 us; speedup 1.0000x reference)
//
#include <hip/hip_runtime.h>
#include <cstdint>
#include <cstddef>

#define DIM 768
#define NHD 12
#define HD  64
#define HH  56
#define WW  56
#define NQ  3136   // 56*56
#define HS  28
#define WSS 28
#define NS  784    // 28*28
#define HK  14
#define WK  14
#define NKK 196    // 14*14
#define NKP 224    // keys padded to 7*32 for PV k-loop
#define VSTR 256   // v row stride in bf16 (512B rows -> complete 128B XOR blocks)

typedef __bf16 bf16x8 __attribute__((ext_vector_type(8)));
typedef __bf16 bf16x4 __attribute__((ext_vector_type(4)));
typedef float  f32x4  __attribute__((ext_vector_type(4)));

// ---------------------------------------------------------------------------
// bijective XCD-aware block swizzle (m204)
__device__ __forceinline__ int xcd_swizzle(int bid, int nwg) {
  const int q = nwg >> 3, r = nwg & 7;
  const int xcd = bid & 7, off = bid >> 3;
  return (xcd < r ? xcd * (q + 1) : r * (q + 1) + (xcd - r) * q) + off;
}

// async global->LDS 16B copy (dest = wave-uniform base + lane*16)
__device__ __forceinline__ void gload_lds16(const void* g, void* l) {
  __builtin_amdgcn_global_load_lds(
      (const __attribute__((address_space(1))) void*)g,
      (__attribute__((address_space(3))) void*)l, 16, 0, 0);
}

__device__ __forceinline__ unsigned pack_bf2(float a, float b) {
  union { __bf16 h; unsigned short u; } lo, hi;
  lo.h = (__bf16)a; hi.h = (__bf16)b;
  return (unsigned)lo.u | ((unsigned)hi.u << 16);
}

// ---------------- bf16 MFMA GEMM: C[M,N] = A[M,K] @ Bt[N,K]^T + bias --------
// 128x128 tile, 4 waves, TRIPLE-buffered global_load_lds with COUNTED vmcnt
// + raw s_barrier (T4). Epilogue goes THROUGH LDS (32x132 f32 slab per i)
// so global stores are row-contiguous: 64B/thread f32, 32B/thread bf16.
// MODE 0: C f32 row-major. MODE 1: Cq bf16 permuted [b][h][n][hd] (q-proj).
// MODE 2: Cq bf16 row-major.
template<int MODE>
__global__ __launch_bounds__(256) void gemm_mfma_kernel(
    const __bf16* __restrict__ A, const __bf16* __restrict__ Bt,
    const float* __restrict__ bias, float* __restrict__ C,
    __bf16* __restrict__ Cq, int M, int N, int K)
{
  __shared__ __bf16 As[3][128 * 32];   // 3 x 8 KB
  __shared__ __bf16 Bs[3][128 * 32];   // 3 x 8 KB (48 KB total)

  const int nX = N >> 7;
  const int bid = xcd_swizzle(blockIdx.x, (M >> 7) * nX);
  const int row0 = (bid / nX) << 7;
  const int col0 = (bid % nX) << 7;

  const int t = threadIdx.x;
  const int lane = t & 63;
  const int w = t >> 6;                 // wave 0..3
  const int wr = w >> 1, wc = w & 1;    // 2x2 wave grid
  const int fr = lane & 15;
  const int fc = lane >> 4;

  // staging: thread t covers rows r0 = t>>2 and r0+64, chunk ch = t&3;
  // source chunk pre-swizzled sc = ch ^ ((r0>>1)&3). LDS dest LINEAR.
  const int r0 = t >> 2;
  const int ch = t & 3;
  const int sc = ch ^ ((r0 >> 1) & 3);
  const __bf16* Ap0 = A + (size_t)(row0 + r0) * K + sc * 8;
  const __bf16* Ap1 = A + (size_t)(row0 + r0 + 64) * K + sc * 8;
  const __bf16* Bp0 = Bt + (size_t)(col0 + r0) * K + sc * 8;
  const __bf16* Bp1 = Bt + (size_t)(col0 + r0 + 64) * K + sc * 8;
  char* Asb = (char*)As;
  char* Bsb = (char*)Bs;
  const int db = w * 1024;

  f32x4 acc[4][4];
#pragma unroll
  for (int i = 0; i < 4; ++i)
#pragma unroll
    for (int j = 0; j < 4; ++j) acc[i][j] = (f32x4){0.f, 0.f, 0.f, 0.f};

  const int keyA = (fr >> 1) & 3;   // fragment-read XOR key (row-derived)

  const int NT = K >> 5;   // K/32 (>= 2 for all our shapes)

  // prologue: stage tiles 0 and 1 into buffers 0 and 1 (8 loads in flight)
  gload_lds16(Ap0, Asb + db);
  gload_lds16(Ap1, Asb + 4096 + db);
  gload_lds16(Bp0, Bsb + db);
  gload_lds16(Bp1, Bsb + 4096 + db);
  {
    const int ko = 1 << 5;
    gload_lds16(Ap0 + ko, Asb + 8192 + db);
    gload_lds16(Ap1 + ko, Asb + 8192 + 4096 + db);
    gload_lds16(Bp0 + ko, Bsb + 8192 + db);
    gload_lds16(Bp1 + ko, Bsb + 8192 + 4096 + db);
  }

  int bcur = 0;        // buffer holding tile kt
  for (int kt = 0; kt < NT; ++kt) {
    // own oldest loads (this tile's) retired; keep next tile's in flight
    if (kt + 1 < NT) {
      asm volatile("s_waitcnt vmcnt(4)" ::: "memory");
    } else {
      asm volatile("s_waitcnt vmcnt(0)" ::: "memory");
    }
    __builtin_amdgcn_s_barrier();   // publish: all waves' tile-kt loads done

    if (kt + 2 < NT) {   // issue tile kt+2 into the buffer read at kt-1
      const int ko = (kt + 2) << 5;
      const int ob = ((bcur + 2) % 3) * 8192;
      gload_lds16(Ap0 + ko, Asb + ob + db);
      gload_lds16(Ap1 + ko, Asb + ob + 4096 + db);
      gload_lds16(Bp0 + ko, Bsb + ob + db);
      gload_lds16(Bp1 + ko, Bsb + ob + 4096 + db);
    }

    const char* Ab = Asb + bcur * 8192;
    const char* Bb = Bsb + bcur * 8192;
    bf16x8 af[4], bfr[4];
#pragma unroll
    for (int i = 0; i < 4; ++i) {
      const int r = wr * 64 + i * 16 + fr;
      af[i] = *(const bf16x8*)(Ab + r * 64 + ((fc ^ keyA) << 4));
    }
#pragma unroll
    for (int j = 0; j < 4; ++j) {
      const int r = wc * 64 + j * 16 + fr;
      bfr[j] = *(const bf16x8*)(Bb + r * 64 + ((fc ^ keyA) << 4));
    }
#pragma unroll
    for (int i = 0; i < 4; ++i)
#pragma unroll
      for (int j = 0; j < 4; ++j)
        acc[i][j] = __builtin_amdgcn_mfma_f32_16x16x32_bf16(af[i], bfr[j], acc[i][j], 0, 0, 0);

    bcur = (bcur == 2) ? 0 : bcur + 1;
  }

  __syncthreads();   // all waves done with LDS tiles; reuse As as f32 staging

  // epilogue through LDS: per i-slab, 32 rows x 132 cols f32 (16.9 KB),
  // then row-contiguous global stores.
  float* eb = (float*)As;
  const int erow = wr * 16 + (fc << 2);    // + r
  const int ecol = wc * 64 + fr;           // + j*16
  const int lr = t >> 3;                   // reader row 0..31
  const int cq = (t & 7) * 16;             // reader col 0..112
#pragma unroll
  for (int i = 0; i < 4; ++i) {
#pragma unroll
    for (int j = 0; j < 4; ++j) {
      const float bv = bias[col0 + ecol + j * 16];
#pragma unroll
      for (int r = 0; r < 4; ++r)
        eb[(erow + r) * 132 + ecol + j * 16] = acc[i][j][r] + bv;
    }
    __syncthreads();   // slab visible

    const int grow = row0 + (lr >> 4) * 64 + i * 16 + (lr & 15);
    const int gcol = col0 + cq;
    const float* src = eb + lr * 132 + cq;
    if (MODE == 0) {
      float* dst = C + (size_t)grow * N + gcol;
#pragma unroll
      for (int q = 0; q < 4; ++q)
        *(float4*)(dst + q * 4) = *(const float4*)(src + q * 4);
    } else {
      __bf16* dst;
      if (MODE == 1) {
        const int b = grow / NQ, n = grow - b * NQ;
        const int h = gcol >> 6, hd = gcol & 63;
        dst = Cq + (((size_t)b * NHD + h) * NQ + n) * HD + hd;
      } else {
        dst = Cq + (size_t)grow * N + gcol;
      }
#pragma unroll
      for (int q = 0; q < 2; ++q) {
        bf16x8 o;
#pragma unroll
        for (int k = 0; k < 8; ++k) o[k] = (__bf16)src[q * 8 + k];
        *(bf16x8*)(dst + q * 8) = o;
      }
    }
    __syncthreads();   // before next slab overwrites eb
  }
}

// ---------------- f32 -> bf16 cast (vectorized, grid-stride) ----------------
__global__ __launch_bounds__(256) void cast_bf16_kernel(
    const float* __restrict__ in, __bf16* __restrict__ out, long n4)
{
  long i = (long)blockIdx.x * 256 + threadIdx.x;
  const long stride = (long)gridDim.x * 256;
  for (; i < n4; i += stride) {
    float4 v = *(const float4*)(in + i * 4);
    bf16x4 o;
    o.x = (__bf16)v.x; o.y = (__bf16)v.y; o.z = (__bf16)v.z; o.w = (__bf16)v.w;
    *(bf16x4*)(out + i * 4) = o;
  }
}

// ---------------- merged weight transpose+cast for q_w / kv_w / proj_w -----
__global__ __launch_bounds__(256) void wt3_cast_kernel(
    const float* __restrict__ q_w, const float* __restrict__ kv_w,
    const float* __restrict__ proj_w, __bf16* __restrict__ wqt,
    __bf16* __restrict__ wkvt, __bf16* __restrict__ wpjt)
{
  const int which = blockIdx.z;
  const float* W = (which == 0) ? q_w : (which == 1) ? kv_w : proj_w;
  __bf16* Wt = (which == 0) ? wqt : (which == 1) ? wkvt : wpjt;
  const int N = (which == 1) ? 2 * DIM : DIM;
  const int n0 = blockIdx.x << 5;
  if (n0 >= N) return;
  const int k0 = blockIdx.y << 5;
  __shared__ float tile[32][33];
  const int tc = threadIdx.x & 31;
  const int tr = threadIdx.x >> 5;   // 0..7
#pragma unroll
  for (int i = 0; i < 4; ++i)
    tile[tr + i * 8][tc] = W[(size_t)(k0 + tr + i * 8) * N + n0 + tc];
  __syncthreads();
#pragma unroll
  for (int i = 0; i < 4; ++i)
    Wt[(size_t)(n0 + tr + i * 8) * DIM + k0 + tc] = (__bf16)tile[tc][tr + i * 8];
}

// ---------------- merged small transposes: up_w -> upt, sr_w -> srt ---------
__global__ __launch_bounds__(256) void misc_tr_kernel(
    const float* __restrict__ upw, float* __restrict__ upt,
    const float* __restrict__ srw, float* __restrict__ srt)
{
  const int i = blockIdx.x * 256 + threadIdx.x;
  if (i < 4 * 9 * DIM) {
    const int c = i % DIM;
    const int rest = i / DIM;
    const int tap = rest % 9, sidx = rest / 9;
    upt[i] = upw[(c * 4 + sidx) * 9 + tap];
  } else {
    const int j = i - 4 * 9 * DIM;
    if (j < 9 * DIM) {
      const int c = j % DIM;
      const int tap = j / DIM;
      srt[j] = srw[c * 9 + tap];
    }
  }
}

// ---------------- pool_q: depthwise 3x3 s1 p1 + LN(64) -----------------------
__global__ __launch_bounds__(256) void pool_q_ln_kernel(
    const __bf16* __restrict__ qp, const float* __restrict__ pqw,
    const float* __restrict__ g, const float* __restrict__ bb,
    __bf16* __restrict__ qf)
{
  const int blk = xcd_swizzle(blockIdx.x, gridDim.x);
  const int bh = blk / HH, y = blk - bh * HH;
  const int lane = threadIdx.x & 63;
  const int w = threadIdx.x >> 6;
  const int x0 = w * (WW / 4);   // 14-px strip

  float wt[9];
#pragma unroll
  for (int tap = 0; tap < 9; ++tap) {
    const int yy = y - 1 + tap / 3;
    wt[tap] = (yy >= 0 && yy < HH) ? pqw[lane * 9 + tap] : 0.f;
  }
  const float gl = g[lane], bl = bb[lane];

  const __bf16* rp0;
  const __bf16* rp1;
  const __bf16* rp2;
  {
    const __bf16* base = qp + (size_t)bh * NQ * HD + lane;
    rp0 = base + (size_t)min(max(y - 1, 0), HH - 1) * WW * HD;
    rp1 = base + (size_t)y * WW * HD;
    rp2 = base + (size_t)min(max(y + 1, 0), HH - 1) * WW * HD;
  }
  auto ldc = [&](int xx, float* d) {
    const float m = (xx >= 0 && xx < WW) ? 1.f : 0.f;
    const int xc = min(max(xx, 0), WW - 1);
    d[0] = m * (float)rp0[(size_t)xc * HD];
    d[1] = m * (float)rp1[(size_t)xc * HD];
    d[2] = m * (float)rp2[(size_t)xc * HD];
  };

  float c0[3], c1[3], c2[3], cn[3];
  ldc(x0 - 1, c0);
  ldc(x0,     c1);
  ldc(x0 + 1, c2);

#pragma unroll
  for (int xi = 0; xi < WW / 4; ++xi) {
    const int x = x0 + xi;
    ldc(x + 2, cn);   // prefetch next column (independent)
    float acc = 0.f;
#pragma unroll
    for (int dy = 0; dy < 3; ++dy) {
      acc = fmaf(wt[dy * 3 + 0], c0[dy], acc);
      acc = fmaf(wt[dy * 3 + 1], c1[dy], acc);
      acc = fmaf(wt[dy * 3 + 2], c2[dy], acc);
    }
    float s = acc, sq = acc * acc;
#pragma unroll
    for (int off = 32; off > 0; off >>= 1) {
      s  += __shfl_xor(s, off);
      sq += __shfl_xor(sq, off);
    }
    const float mean = s * (1.f / 64.f);
    const float var  = sq * (1.f / 64.f) - mean * mean;
    const float rstd = rsqrtf(var + 1e-5f);
    qf[((size_t)bh * NQ + y * WW + x) * HD + lane] =
        (__bf16)((acc - mean) * rstd * gl + bl);
#pragma unroll
    for (int dy = 0; dy < 3; ++dy) {
      c0[dy] = c1[dy]; c1[dy] = c2[dy]; c2[dy] = cn[dy];
    }
  }
}

// ---------------- sr: depthwise 3x3 s2 p1 (+bias) + LN(768), bf16 in/out ----
__global__ __launch_bounds__(256) void sr_ln_kernel(
    const __bf16* __restrict__ x, const float* __restrict__ srt,
    const float* __restrict__ srb, const float* __restrict__ g,
    const float* __restrict__ bb, __bf16* __restrict__ out)
{
  const int row = xcd_swizzle(blockIdx.x, gridDim.x);   // b*784 + ns
  const int b = row / NS, ns = row - b * NS;
  const int ys = ns / WSS, xs = ns - ys * WSS;
  const int t = threadIdx.x;

  float fm[9];
  size_t off9[9];
#pragma unroll
  for (int tap = 0; tap < 9; ++tap) {
    const int yy = 2 * ys - 1 + tap / 3;
    const int xx = 2 * xs - 1 + tap % 3;
    fm[tap] = (yy >= 0 && yy < HH && xx >= 0 && xx < WW) ? 1.f : 0.f;
    const int yyc = min(max(yy, 0), HH - 1);
    const int xxc = min(max(xx, 0), WW - 1);
    off9[tap] = ((size_t)b * NQ + yyc * WW + xxc) * DIM;
  }

  float vals[3];
  float lsum = 0.f, lsq = 0.f;
#pragma unroll
  for (int i = 0; i < 3; ++i) {
    const int c = t + i * 256;
    float v9[9];
#pragma unroll
    for (int tap = 0; tap < 9; ++tap) v9[tap] = (float)x[off9[tap] + c];
    float acc = srb[c];
#pragma unroll
    for (int tap = 0; tap < 9; ++tap)
      acc = fmaf(srt[tap * DIM + c] * fm[tap], v9[tap], acc);
    vals[i] = acc;
    lsum += acc;
    lsq = fmaf(acc, acc, lsq);
  }
#pragma unroll
  for (int off = 32; off > 0; off >>= 1) {
    lsum += __shfl_xor(lsum, off);
    lsq  += __shfl_xor(lsq, off);
  }
  __shared__ float s1[4], s2[4];
  if ((t & 63) == 0) { s1[t >> 6] = lsum; s2[t >> 6] = lsq; }
  __syncthreads();
  const float S  = s1[0] + s1[1] + s1[2] + s1[3];
  const float SQ = s2[0] + s2[1] + s2[2] + s2[3];
  const float mean = S * (1.f / 768.f);
  const float var  = SQ * (1.f / 768.f) - mean * mean;
  const float rstd = rsqrtf(var + 1e-6f);
#pragma unroll
  for (int i = 0; i < 3; ++i) {
    const int c = t + i * 256;
    out[(size_t)row * DIM + c] = (__bf16)((vals[i] - mean) * rstd * g[c] + bb[c]);
  }
}

// ---------------- pool_k + pool_v merged: conv s2 + LN(64) ------------------
// y==0: K -> kpb[bh][nk][lane^((nk&7)<<3)]       (XOR-swizzled rows, 128B)
// y==1: V -> vtb[bh][lane][nk^((lane&7)<<3)]     (transposed, VSTR rows)
__global__ __launch_bounds__(256) void pool_kv_ln_kernel(
    const __bf16* __restrict__ kv, const float* __restrict__ pkw,
    const float* __restrict__ pvw, const float* __restrict__ kg,
    const float* __restrict__ kbb, const float* __restrict__ vg,
    const float* __restrict__ vbb, __bf16* __restrict__ kpb,
    __bf16* __restrict__ vtb)
{
  const int isv = blockIdx.y;
  const float* pw = isv ? pvw : pkw;
  const float* g  = isv ? vg  : kg;
  const float* bb = isv ? vbb : kbb;
  const int coloff = isv ? DIM : 0;

  const int lane = threadIdx.x & 63;
  const int r = blockIdx.x * 4 + (threadIdx.x >> 6);   // bh*224 + nk
  const int bh = r / NKP;
  const int nk = r - bh * NKP;

  float val = 0.f;
  if (nk < NKK) {
    const int b = bh / NHD, h = bh - b * NHD;
    const int yk = nk / WK, xk = nk - yk * WK;
    float acc = 0.f;
#pragma unroll
    for (int dy = 0; dy < 3; ++dy) {
      const int yy = 2 * yk - 1 + dy;
      if (yy < 0 || yy >= HS) continue;
#pragma unroll
      for (int dx = 0; dx < 3; ++dx) {
        const int xx = 2 * xk - 1 + dx;
        if (xx < 0 || xx >= WSS) continue;
        acc = fmaf(pw[lane * 9 + dy * 3 + dx],
                   (float)kv[((size_t)b * NS + yy * WSS + xx) * (2 * DIM) + coloff + h * HD + lane], acc);
      }
    }
    float s = acc, sq = acc * acc;
#pragma unroll
    for (int off = 32; off > 0; off >>= 1) {
      s  += __shfl_xor(s, off);
      sq += __shfl_xor(sq, off);
    }
    const float mean = s * (1.f / 64.f);
    const float var  = sq * (1.f / 64.f) - mean * mean;
    const float rstd = rsqrtf(var + 1e-5f);
    val = (acc - mean) * rstd * g[lane] + bb[lane];
  }
  if (!isv) {
    kpb[(size_t)bh * NKP * HD + nk * HD + (lane ^ ((nk & 7) << 3))] = (__bf16)val;
  } else {
    vtb[(size_t)bh * HD * VSTR + lane * VSTR + (nk ^ ((lane & 7) << 3))] = (__bf16)val;
  }
}

// ---------------- MFMA attention core ---------------------------------------
// ONE 32KB LDS region: K staged (gload_lds) -> QK (swapped: D[key][q]) ->
// barrier -> V staged into SAME region (latency hidden under softmax) ->
// softmax + P packed to bf16 dwords in REGISTERS -> PV with A-fragments
// redistributed via __shfl (compile-time pk indices only). No-max softmax.
__global__ __launch_bounds__(256) void attn_mfma_kernel(
    const __bf16* __restrict__ qf, const __bf16* __restrict__ kpb,
    const __bf16* __restrict__ vtb, __bf16* __restrict__ out)
{
  __shared__ __bf16 kv_lds[16384];   // 32,768 B: K (28,672B) then V (32,768B)
  const int bh = blockIdx.y;
  const int qt = blockIdx.x;
  const int t = threadIdx.x;
  const int lane = t & 63, w = t >> 6;
  const int fr = lane & 15;   // fragment row (key row in QK; q/d row in PV)
  const int fg = lane >> 4;   // k-chunk group
  const int q0 = qt * 64 + w * 16;
  const int sw = (fr & 7) << 4;   // XOR swizzle key (byte)

  // q loads (regs) — issued before staging, drained by the first barrier
  const __bf16* qbase = qf + ((size_t)bh * NQ + q0) * HD;
  const bf16x8 aq0 = *(const bf16x8*)(qbase + fr * HD + fg * 8);
  const bf16x8 aq1 = *(const bf16x8*)(qbase + fr * HD + 32 + fg * 8);

  // stage K (7x16B/thread), all independent
  char* kl = (char*)kv_lds;
  {
    const __bf16* kgp = kpb + (size_t)bh * (NKP * HD);
#pragma unroll
    for (int i = 0; i < 7; ++i)
      gload_lds16(kgp + (i * 256 + w * 64 + lane) * 8, kl + i * 4096 + w * 1024);
  }
  __syncthreads();   // K in LDS; q in regs

  // QK^T from LDS — SWAPPED operands: D[key][q]
  f32x4 s[13];
#pragma unroll
  for (int n = 0; n < 13; ++n) {
    const int rowb = (n * 16 + fr) << 7;   // 128B K rows
    const bf16x8 b0 = *(const bf16x8*)(kl + rowb + ((fg << 4) ^ sw));
    const bf16x8 b1 = *(const bf16x8*)(kl + rowb + (((fg << 4) + 64) ^ sw));
    f32x4 c = (f32x4){0.f, 0.f, 0.f, 0.f};
    c = __builtin_amdgcn_mfma_f32_16x16x32_bf16(b0, aq0, c, 0, 0, 0);
    c = __builtin_amdgcn_mfma_f32_16x16x32_bf16(b1, aq1, c, 0, 0, 0);
    s[n] = c;   // lane: keys n*16 + 4*fg + r (r=0..3), q-col = fr
  }
  __syncthreads();   // all waves done reading K; region becomes V

  // stage V (8x16B/thread) into the SAME region — latency hides under softmax
  {
    const __bf16* vgp = vtb + (size_t)bh * (HD * VSTR);
#pragma unroll
    for (int i = 0; i < 8; ++i)
      gload_lds16(vgp + (i * 256 + w * 64 + lane) * 8, kl + i * 4096 + w * 1024);
  }

  // softmax (no max): exp per score, P packed to bf16 dwords in registers
  const float scale = 0.125f;
  unsigned pk[28];
  float sum = 0.f;
#pragma unroll
  for (int n = 0; n < 13; ++n) {
    float e0 = __expf(s[n][0] * scale);
    float e1 = __expf(s[n][1] * scale);
    float e2 = __expf(s[n][2] * scale);
    float e3 = __expf(s[n][3] * scale);
    if (n == 12 && fg >= 1) { e0 = e1 = e2 = e3 = 0.f; }   // keys >=196 invalid
    sum += (e0 + e1) + (e2 + e3);
    pk[2 * n]     = pack_bf2(e0, e1);
    pk[2 * n + 1] = pack_bf2(e2, e3);
  }
  pk[26] = 0u; pk[27] = 0u;   // keys 208..223
  sum += __shfl_xor(sum, 16);
  sum += __shfl_xor(sum, 32);
  const float pinvL = 1.f / sum;   // 1/sum for q-row fr (all fg agree)

  __syncthreads();   // V ready in LDS

  // PV: A-fragment (P) redistributed via shfl; V from LDS.
  const int L1 = ((fg & 1) << 5) | fr;
  const int L2 = L1 + 16;
  const bool hi = (fg >= 2);
  f32x4 acc2[4];
#pragma unroll
  for (int dt = 0; dt < 4; ++dt) acc2[dt] = (f32x4){0.f, 0.f, 0.f, 0.f};
  const char* vl = (const char*)kv_lds;
#pragma unroll
  for (int ks = 0; ks < 7; ++ks) {
    const unsigned d0a = __shfl(pk[4 * ks + 0], L1), d0b = __shfl(pk[4 * ks + 2], L1);
    const unsigned d1a = __shfl(pk[4 * ks + 1], L1), d1b = __shfl(pk[4 * ks + 3], L1);
    const unsigned d2a = __shfl(pk[4 * ks + 0], L2), d2b = __shfl(pk[4 * ks + 2], L2);
    const unsigned d3a = __shfl(pk[4 * ks + 1], L2), d3b = __shfl(pk[4 * ks + 3], L2);
    uint4 pu;
    pu.x = hi ? d0b : d0a;
    pu.y = hi ? d1b : d1a;
    pu.z = hi ? d2b : d2a;
    pu.w = hi ? d3b : d3a;
    const bf16x8 pabf = __builtin_bit_cast(bf16x8, pu);
#pragma unroll
    for (int dt = 0; dt < 4; ++dt) {
      const bf16x8 bv = *(const bf16x8*)(vl + (dt * 16 + fr) * (VSTR * 2) + ((ks * 64 + (fg << 4)) ^ sw));
      acc2[dt] = __builtin_amdgcn_mfma_f32_16x16x32_bf16(pabf, bv, acc2[dt], 0, 0, 0);
    }
  }

  // epilogue: out row q = q0 + 4*fg + r, col d = dt*16 + fr.
  float pr[4];
#pragma unroll
  for (int r = 0; r < 4; ++r)
    pr[r] = __shfl(pinvL, (fg << 4) | (fg * 4 + r));
  const int b = bh / NHD, h = bh - b * NHD;
#pragma unroll
  for (int dt = 0; dt < 4; ++dt)
#pragma unroll
    for (int r = 0; r < 4; ++r)
      out[((size_t)b * NQ + q0 + 4 * fg + r) * DIM + h * HD + dt * 16 + fr] =
          (__bf16)(acc2[dt][r] * pr[r]);
}

// ---------------- identity path + add + LN -> bf16 proj input ---------------
#define XCH 2    // strips per ys row

__global__ __launch_bounds__(256) void idn_add_ln_kernel(
    const __bf16* __restrict__ kv, const float* __restrict__ upt,
    const float* __restrict__ upb, const float* __restrict__ g,
    const float* __restrict__ bb, const __bf16* __restrict__ io,
    __bf16* __restrict__ pj)
{
  int idx = xcd_swizzle(blockIdx.x, gridDim.x);
  const int chunk = idx & (XCH - 1); idx >>= 1;
  const int ys = idx % HS; idx /= HS;
  const int sidx = idx & 3;
  const int b = idx >> 2;
  const int sy = sidx >> 1, sx = sidx & 1;
  const int y = 2 * ys + sy;
  const int t = threadIdx.x;
  const int w = t >> 6;

  float wreg[3][9], ubias[3], gg[3], gb[3];
#pragma unroll
  for (int i = 0; i < 3; ++i) {
    const int c = t + i * 256;
    ubias[i] = upb[c * 4 + sidx];
    gg[i] = g[c];
    gb[i] = bb[c];
#pragma unroll
    for (int tap = 0; tap < 9; ++tap) {
      const int yy = ys - 1 + tap / 3;
      const float f = (yy >= 0 && yy < HS) ? 1.f : 0.f;   // fold row-OOB into weight
      wreg[i][tap] = upt[(sidx * 9 + tap) * DIM + c] * f;  // coalesced
    }
  }

  __shared__ __bf16 vals_lds[14][DIM];   // 21,504 B
  __shared__ float s1[14][4], s2[14][4];
  const int xs0 = chunk * 14;

  // clamped row indices (row-OOB contributes 0 via zeroed weights)
  const int y0 = max(ys - 1, 0), y1 = ys, y2 = min(ys + 1, HS - 1);
  const __bf16* vb0 = kv + ((size_t)(b * NS + y0 * WSS)) * (2 * DIM) + DIM + t;
  const __bf16* vb1 = kv + ((size_t)(b * NS + y1 * WSS)) * (2 * DIM) + DIM + t;
  const __bf16* vb2 = kv + ((size_t)(b * NS + y2 * WSS)) * (2 * DIM) + DIM + t;

  // unconditional clamped column load, col-OOB masked by multiply
  auto ldcol = [&](int ch, int p, float* dst) {
    const float m = (p >= 0 && p < WSS) ? 1.f : 0.f;
    const int xx = min(max(p, 0), WSS - 1);
    const size_t off = (size_t)xx * (2 * DIM) + ch * 256;
    dst[0] = m * (float)vb0[off];
    dst[1] = m * (float)vb1[off];
    dst[2] = m * (float)vb2[off];
  };

  float c0[3][3], c1[3][3], c2[3][3], cn[3][3];
#pragma unroll
  for (int ch = 0; ch < 3; ++ch) {
    ldcol(ch, xs0 - 1, c0[ch]);
    ldcol(ch, xs0,     c1[ch]);
    ldcol(ch, xs0 + 1, c2[ch]);
  }

#pragma unroll
  for (int xi = 0; xi < 14; ++xi) {
    const int xs = xs0 + xi;
#pragma unroll
    for (int ch = 0; ch < 3; ++ch) ldcol(ch, xs + 2, cn[ch]);
    float lsum = 0.f, lsq = 0.f;
#pragma unroll
    for (int ch = 0; ch < 3; ++ch) {
      float acc = ubias[ch];
#pragma unroll
      for (int dy = 0; dy < 3; ++dy) {
        acc = fmaf(wreg[ch][dy * 3 + 0], c0[ch][dy], acc);
        acc = fmaf(wreg[ch][dy * 3 + 1], c1[ch][dy], acc);
        acc = fmaf(wreg[ch][dy * 3 + 2], c2[ch][dy], acc);
      }
      vals_lds[xi][t + ch * 256] = (__bf16)acc;
      lsum += acc;
      lsq = fmaf(acc, acc, lsq);
    }
#pragma unroll
    for (int off = 32; off > 0; off >>= 1) {
      lsum += __shfl_xor(lsum, off);
      lsq  += __shfl_xor(lsq, off);
    }
    if ((t & 63) == 0) { s1[xi][w] = lsum; s2[xi][w] = lsq; }
#pragma unroll
    for (int ch = 0; ch < 3; ++ch)
#pragma unroll
      for (int dy = 0; dy < 3; ++dy) {
        c0[ch][dy] = c1[ch][dy];
        c1[ch][dy] = c2[ch][dy];
        c2[ch][dy] = cn[ch][dy];
      }
  }
  __syncthreads();   // ONE barrier: all conv values + partials in LDS

#pragma unroll
  for (int xi = 0; xi < 14; ++xi) {
    const float S  = s1[xi][0] + s1[xi][1] + s1[xi][2] + s1[xi][3];
    const float SQ = s2[xi][0] + s2[xi][1] + s2[xi][2] + s2[xi][3];
    const float mean = S * (1.f / 768.f);
    const float var  = SQ * (1.f / 768.f) - mean * mean;
    const float rstd = rsqrtf(var + 1e-6f);
    const int x = 2 * (xs0 + xi) + sx;
    const size_t row = (size_t)b * NQ + y * WW + x;
#pragma unroll
    for (int ch = 0; ch < 3; ++ch) {
      const int c = t + ch * 256;
      pj[row * DIM + c] =
          (__bf16)((float)io[row * DIM + c] +
                   ((float)vals_lds[xi][c] - mean) * rstd * gg[ch] + gb[ch]);
    }
  }
}

// =============================================================================
extern "C" void kernel_launch(void* const* d_in, const int* in_sizes, int n_in,
                              void* d_out, int out_size, void* d_ws, size_t ws_size,
                              hipStream_t stream)
{
  const float* x      = (const float*)d_in[0];
  const float* q_w    = (const float*)d_in[1];
  const float* q_b    = (const float*)d_in[2];
  const float* kv_w   = (const float*)d_in[3];
  const float* kv_b   = (const float*)d_in[4];
  const float* sr_w   = (const float*)d_in[5];
  const float* sr_b   = (const float*)d_in[6];
  const float* srn_g  = (const float*)d_in[7];
  const float* srn_b  = (const float*)d_in[8];
  const float* up_w   = (const float*)d_in[9];
  const float* up_b   = (const float*)d_in[10];
  const float* upn_g  = (const float*)d_in[11];
  const float* upn_b  = (const float*)d_in[12];
  const float* proj_w = (const float*)d_in[13];
  const float* proj_b = (const float*)d_in[14];
  const float* pq_w   = (const float*)d_in[15];
  const float* pk_w   = (const float*)d_in[16];
  const float* pv_w   = (const float*)d_in[17];
  const float* nq_g   = (const float*)d_in[18];
  const float* nq_b   = (const float*)d_in[19];
  const float* nk_g   = (const float*)d_in[20];
  const float* nk_b   = (const float*)d_in[21];
  const float* nv_g   = (const float*)d_in[22];
  const float* nv_b   = (const float*)d_in[23];

  const int B = in_sizes[0] / (NQ * DIM);   // 8
  const int M1 = B * NQ;                    // 25088
  const int M2 = B * NS;                    // 6272

  // workspace layout (bytes)
  char* p = (char*)d_ws;
  __bf16* xb    = (__bf16*)p;  p += (size_t)M1 * DIM * 2;        // x bf16; reused as pjin
  float*  qproj = (float*)p;   p += (size_t)M1 * DIM * 4;        // qp bf16 / attnout bf16
  __bf16* qf    = (__bf16*)p;  p += (size_t)M1 * DIM * 2;        // pooled+LN q (bf16)
  __bf16* xsln  = (__bf16*)p;  p += (size_t)M2 * DIM * 2;        // sr+LN out (bf16)
  __bf16* kvb   = (__bf16*)p;  p += (size_t)M2 * 2 * DIM * 2;    // kv-proj out (bf16)
  __bf16* kpb   = (__bf16*)p;  p += (size_t)B * NHD * NKP * HD * 2;   // pooled k, swizzled
  __bf16* vtb   = (__bf16*)p;  p += (size_t)B * NHD * HD * VSTR * 2;  // pooled v, transposed+swizzled
  __bf16* wqt   = (__bf16*)p;  p += (size_t)DIM * DIM * 2;       // q_w^T bf16 [N][K]
  __bf16* wkvt  = (__bf16*)p;  p += (size_t)DIM * 2 * DIM * 2;   // kv_w^T bf16
  __bf16* wpjt  = (__bf16*)p;  p += (size_t)DIM * DIM * 2;       // proj_w^T bf16
  float*  upt   = (float*)p;   p += (size_t)4 * 9 * DIM * 4;     // up_w transposed [sidx][tap][c]
  float*  srt   = (float*)p;   p += (size_t)9 * DIM * 4;         // sr_w transposed [tap][c]
  __bf16* qp      = (__bf16*)qproj;  // bf16 permuted q-proj (dead before attnout live)
  __bf16* attnout = (__bf16*)qproj;  // bf16 attention output (after qp dead)
  __bf16* pjin    = xb;

  dim3 blk(256);

  // 0. casts / weight transposes (merged: 3 dispatches)
  cast_bf16_kernel<<<2048, blk, 0, stream>>>(x, xb, (long)M1 * DIM / 4);
  wt3_cast_kernel<<<dim3(48, 24, 3), blk, 0, stream>>>(
      q_w, kv_w, proj_w, wqt, wkvt, wpjt);
  misc_tr_kernel<<<(5 * 9 * DIM + 255) / 256, blk, 0, stream>>>(
      up_w, upt, sr_w, srt);

  // 1. q projection (bf16 MFMA, triple-buf counted-vmcnt) -> qp bf16 permuted
  gemm_mfma_kernel<1><<<(M1 / 128) * (DIM / 128), blk, 0, stream>>>(
      xb, wqt, q_b, nullptr, qp, M1, DIM, DIM);

  // 2. pool_q conv + LN(64) -> bf16 (sliding-window, unconditional loads)
  pool_q_ln_kernel<<<B * NHD * HH, blk, 0, stream>>>(
      qp, pq_w, nq_g, nq_b, qf);

  // 3. spatial reduction conv + LN(768) -> bf16 (unconditional loads)
  sr_ln_kernel<<<B * NS, blk, 0, stream>>>(
      xb, srt, sr_b, srn_g, srn_b, xsln);

  // 4. kv projection (bf16 MFMA) -> bf16 row-major
  gemm_mfma_kernel<2><<<(M2 / 128) * (2 * DIM / 128), blk, 0, stream>>>(
      xsln, wkvt, kv_b, nullptr, kvb, M2, 2 * DIM, DIM);

  // 5. pool k (swizzled [bh][224][64]) and v (transposed+swizzled [bh][64][256])
  pool_kv_ln_kernel<<<dim3((B * NHD * NKP) / 4, 2), blk, 0, stream>>>(
      kvb, pk_w, pv_w, nk_g, nk_b, nv_g, nv_b, kpb, vtb);

  // 6. MFMA attention core -> attnout (bf16; 32KB LDS, P in registers)
  attn_mfma_kernel<<<dim3(NQ / 64, B * NHD), blk, 0, stream>>>(
      qf, kpb, vtb, attnout);

  // 7. identity path + add -> bf16 proj input (reuses xb region)
  idn_add_ln_kernel<<<B * 4 * HS * XCH, blk, 0, stream>>>(
      kvb, upt, up_b, upn_g, upn_b, attnout, pjin);

  // 8. output projection (bf16 MFMA) -> d_out (f32)
  gemm_mfma_kernel<0><<<(M1 / 128) * (DIM / 128), blk, 0, stream>>>(
      pjin, wpjt, proj_b, (float*)d_out, nullptr, M1, DIM, DIM);
}

// Round 19
// 318.629 us; speedup vs baseline: 1.0541x; 1.0541x over previous
//
#include <hip/hip_runtime.h>
#include <cstdint>
#include <cstddef>

#define DIM 768
#define NHD 12
#define HD  64
#define HH  56
#define WW  56
#define NQ  3136   // 56*56
#define HS  28
#define WSS 28
#define NS  784    // 28*28
#define HK  14
#define WK  14
#define NKK 196    // 14*14
#define NKP 224    // keys padded to 7*32 for PV k-loop
#define VSTR 256   // v row stride in bf16 (512B rows -> complete 128B XOR blocks)

typedef __bf16 bf16x8 __attribute__((ext_vector_type(8)));
typedef __bf16 bf16x4 __attribute__((ext_vector_type(4)));
typedef float  f32x4  __attribute__((ext_vector_type(4)));

// ---------------------------------------------------------------------------
// bijective XCD-aware block swizzle (m204)
__device__ __forceinline__ int xcd_swizzle(int bid, int nwg) {
  const int q = nwg >> 3, r = nwg & 7;
  const int xcd = bid & 7, off = bid >> 3;
  return (xcd < r ? xcd * (q + 1) : r * (q + 1) + (xcd - r) * q) + off;
}

// async global->LDS 16B copy (dest = wave-uniform base + lane*16)
__device__ __forceinline__ void gload_lds16(const void* g, void* l) {
  __builtin_amdgcn_global_load_lds(
      (const __attribute__((address_space(1))) void*)g,
      (__attribute__((address_space(3))) void*)l, 16, 0, 0);
}

__device__ __forceinline__ unsigned pack_bf2(float a, float b) {
  union { __bf16 h; unsigned short u; } lo, hi;
  lo.h = (__bf16)a; hi.h = (__bf16)b;
  return (unsigned)lo.u | ((unsigned)hi.u << 16);
}

// ---------------- bf16 MFMA GEMM: C[M,N] = A[M,K] @ Bt[N,K]^T + bias --------
// 128x128 tile, 4 waves, TRIPLE-buffered global_load_lds with COUNTED vmcnt
// + raw s_barrier (T4): the barrier never drains the in-flight prefetch.
// Per K-step: s_waitcnt vmcnt(4) -> s_barrier -> issue kt+2's 4 loads ->
// ds_read + 16 MFMA. Chunk-XOR both-sides swizzle (conflict-free, r15).
// MODE 0: C f32 row-major (NONTEMPORAL stores — d_out never re-read).
// MODE 1: Cq bf16 permuted [b][h][n][hd] (q-proj). MODE 2: Cq bf16 row-major.
template<int MODE>
__global__ __launch_bounds__(256) void gemm_mfma_kernel(
    const __bf16* __restrict__ A, const __bf16* __restrict__ Bt,
    const float* __restrict__ bias, float* __restrict__ C,
    __bf16* __restrict__ Cq, int M, int N, int K)
{
  __shared__ __bf16 As[3][128 * 32];   // 3 x 8 KB
  __shared__ __bf16 Bs[3][128 * 32];   // 3 x 8 KB (48 KB total)

  const int nX = N >> 7;
  const int bid = xcd_swizzle(blockIdx.x, (M >> 7) * nX);
  const int row0 = (bid / nX) << 7;
  const int col0 = (bid % nX) << 7;

  const int t = threadIdx.x;
  const int lane = t & 63;
  const int w = t >> 6;                 // wave 0..3
  const int wr = w >> 1, wc = w & 1;    // 2x2 wave grid
  const int fr = lane & 15;
  const int fc = lane >> 4;

  // staging: thread t covers rows r0 = t>>2 and r0+64, chunk ch = t&3;
  // source chunk pre-swizzled sc = ch ^ ((r0>>1)&3). LDS dest LINEAR.
  const int r0 = t >> 2;
  const int ch = t & 3;
  const int sc = ch ^ ((r0 >> 1) & 3);
  const __bf16* Ap0 = A + (size_t)(row0 + r0) * K + sc * 8;
  const __bf16* Ap1 = A + (size_t)(row0 + r0 + 64) * K + sc * 8;
  const __bf16* Bp0 = Bt + (size_t)(col0 + r0) * K + sc * 8;
  const __bf16* Bp1 = Bt + (size_t)(col0 + r0 + 64) * K + sc * 8;
  char* Asb = (char*)As;
  char* Bsb = (char*)Bs;
  const int db = w * 1024;

  f32x4 acc[4][4];
#pragma unroll
  for (int i = 0; i < 4; ++i)
#pragma unroll
    for (int j = 0; j < 4; ++j) acc[i][j] = (f32x4){0.f, 0.f, 0.f, 0.f};

  const int keyA = (fr >> 1) & 3;   // fragment-read XOR key (row-derived)

  const int NT = K >> 5;   // K/32 (>= 2 for all our shapes)

  // prologue: stage tiles 0 and 1 into buffers 0 and 1 (8 loads in flight)
  gload_lds16(Ap0, Asb + db);
  gload_lds16(Ap1, Asb + 4096 + db);
  gload_lds16(Bp0, Bsb + db);
  gload_lds16(Bp1, Bsb + 4096 + db);
  {
    const int ko = 1 << 5;
    gload_lds16(Ap0 + ko, Asb + 8192 + db);
    gload_lds16(Ap1 + ko, Asb + 8192 + 4096 + db);
    gload_lds16(Bp0 + ko, Bsb + 8192 + db);
    gload_lds16(Bp1 + ko, Bsb + 8192 + 4096 + db);
  }

  int bcur = 0;        // buffer holding tile kt
  for (int kt = 0; kt < NT; ++kt) {
    // own oldest loads (this tile's) retired; keep next tile's in flight
    if (kt + 1 < NT) {
      asm volatile("s_waitcnt vmcnt(4)" ::: "memory");
    } else {
      asm volatile("s_waitcnt vmcnt(0)" ::: "memory");
    }
    __builtin_amdgcn_s_barrier();   // publish: all waves' tile-kt loads done

    if (kt + 2 < NT) {   // issue tile kt+2 into the buffer read at kt-1
      const int ko = (kt + 2) << 5;
      const int ob = ((bcur + 2) % 3) * 8192;
      gload_lds16(Ap0 + ko, Asb + ob + db);
      gload_lds16(Ap1 + ko, Asb + ob + 4096 + db);
      gload_lds16(Bp0 + ko, Bsb + ob + db);
      gload_lds16(Bp1 + ko, Bsb + ob + 4096 + db);
    }

    const char* Ab = Asb + bcur * 8192;
    const char* Bb = Bsb + bcur * 8192;
    bf16x8 af[4], bfr[4];
#pragma unroll
    for (int i = 0; i < 4; ++i) {
      const int r = wr * 64 + i * 16 + fr;
      af[i] = *(const bf16x8*)(Ab + r * 64 + ((fc ^ keyA) << 4));
    }
#pragma unroll
    for (int j = 0; j < 4; ++j) {
      const int r = wc * 64 + j * 16 + fr;
      bfr[j] = *(const bf16x8*)(Bb + r * 64 + ((fc ^ keyA) << 4));
    }
#pragma unroll
    for (int i = 0; i < 4; ++i)
#pragma unroll
      for (int j = 0; j < 4; ++j)
        acc[i][j] = __builtin_amdgcn_mfma_f32_16x16x32_bf16(af[i], bfr[j], acc[i][j], 0, 0, 0);

    bcur = (bcur == 2) ? 0 : bcur + 1;
  }

  const int orow = row0 + wr * 64 + ((lane >> 4) << 2);
  const int ocol = col0 + wc * 64 + (lane & 15);
#pragma unroll
  for (int j = 0; j < 4; ++j) {
    const int col = ocol + j * 16;
    const float bv = bias[col];
#pragma unroll
    for (int i = 0; i < 4; ++i)
#pragma unroll
      for (int r = 0; r < 4; ++r) {
        const int rrow = orow + i * 16 + r;
        if (MODE == 0) {
          __builtin_nontemporal_store(acc[i][j][r] + bv,
                                      C + (size_t)rrow * N + col);
        } else if (MODE == 1) {
          const int b = rrow / NQ, n = rrow - b * NQ;
          const int h = col >> 6, hd = col & 63;
          Cq[(((size_t)b * NHD + h) * NQ + n) * HD + hd] = (__bf16)(acc[i][j][r] + bv);
        } else {
          Cq[(size_t)rrow * N + col] = (__bf16)(acc[i][j][r] + bv);
        }
      }
  }
}

// ---------------- f32 -> bf16 cast (vectorized, grid-stride) ----------------
__global__ __launch_bounds__(256) void cast_bf16_kernel(
    const float* __restrict__ in, __bf16* __restrict__ out, long n4)
{
  long i = (long)blockIdx.x * 256 + threadIdx.x;
  const long stride = (long)gridDim.x * 256;
  for (; i < n4; i += stride) {
    float4 v = *(const float4*)(in + i * 4);
    bf16x4 o;
    o.x = (__bf16)v.x; o.y = (__bf16)v.y; o.z = (__bf16)v.z; o.w = (__bf16)v.w;
    *(bf16x4*)(out + i * 4) = o;
  }
}

// ---------------- merged weight transpose+cast for q_w / kv_w / proj_w -----
__global__ __launch_bounds__(256) void wt3_cast_kernel(
    const float* __restrict__ q_w, const float* __restrict__ kv_w,
    const float* __restrict__ proj_w, __bf16* __restrict__ wqt,
    __bf16* __restrict__ wkvt, __bf16* __restrict__ wpjt)
{
  const int which = blockIdx.z;
  const float* W = (which == 0) ? q_w : (which == 1) ? kv_w : proj_w;
  __bf16* Wt = (which == 0) ? wqt : (which == 1) ? wkvt : wpjt;
  const int N = (which == 1) ? 2 * DIM : DIM;
  const int n0 = blockIdx.x << 5;
  if (n0 >= N) return;
  const int k0 = blockIdx.y << 5;
  __shared__ float tile[32][33];
  const int tc = threadIdx.x & 31;
  const int tr = threadIdx.x >> 5;   // 0..7
#pragma unroll
  for (int i = 0; i < 4; ++i)
    tile[tr + i * 8][tc] = W[(size_t)(k0 + tr + i * 8) * N + n0 + tc];
  __syncthreads();
#pragma unroll
  for (int i = 0; i < 4; ++i)
    Wt[(size_t)(n0 + tr + i * 8) * DIM + k0 + tc] = (__bf16)tile[tc][tr + i * 8];
}

// ---------------- merged small transposes: up_w -> upt, sr_w -> srt ---------
__global__ __launch_bounds__(256) void misc_tr_kernel(
    const float* __restrict__ upw, float* __restrict__ upt,
    const float* __restrict__ srw, float* __restrict__ srt)
{
  const int i = blockIdx.x * 256 + threadIdx.x;
  if (i < 4 * 9 * DIM) {
    const int c = i % DIM;
    const int rest = i / DIM;
    const int tap = rest % 9, sidx = rest / 9;
    upt[i] = upw[(c * 4 + sidx) * 9 + tap];
  } else {
    const int j = i - 4 * 9 * DIM;
    if (j < 9 * DIM) {
      const int c = j % DIM;
      const int tap = j / DIM;
      srt[j] = srw[c * 9 + tap];
    }
  }
}

// ---------------- pool_q: depthwise 3x3 s1 p1 + LN(64) -----------------------
__global__ __launch_bounds__(256) void pool_q_ln_kernel(
    const __bf16* __restrict__ qp, const float* __restrict__ pqw,
    const float* __restrict__ g, const float* __restrict__ bb,
    __bf16* __restrict__ qf)
{
  const int blk = xcd_swizzle(blockIdx.x, gridDim.x);
  const int bh = blk / HH, y = blk - bh * HH;
  const int lane = threadIdx.x & 63;
  const int w = threadIdx.x >> 6;
  const int x0 = w * (WW / 4);   // 14-px strip

  float wt[9];
#pragma unroll
  for (int tap = 0; tap < 9; ++tap) {
    const int yy = y - 1 + tap / 3;
    wt[tap] = (yy >= 0 && yy < HH) ? pqw[lane * 9 + tap] : 0.f;
  }
  const float gl = g[lane], bl = bb[lane];

  const __bf16* rp0;
  const __bf16* rp1;
  const __bf16* rp2;
  {
    const __bf16* base = qp + (size_t)bh * NQ * HD + lane;
    rp0 = base + (size_t)min(max(y - 1, 0), HH - 1) * WW * HD;
    rp1 = base + (size_t)y * WW * HD;
    rp2 = base + (size_t)min(max(y + 1, 0), HH - 1) * WW * HD;
  }
  auto ldc = [&](int xx, float* d) {
    const float m = (xx >= 0 && xx < WW) ? 1.f : 0.f;
    const int xc = min(max(xx, 0), WW - 1);
    d[0] = m * (float)rp0[(size_t)xc * HD];
    d[1] = m * (float)rp1[(size_t)xc * HD];
    d[2] = m * (float)rp2[(size_t)xc * HD];
  };

  float c0[3], c1[3], c2[3], cn[3];
  ldc(x0 - 1, c0);
  ldc(x0,     c1);
  ldc(x0 + 1, c2);

#pragma unroll
  for (int xi = 0; xi < WW / 4; ++xi) {
    const int x = x0 + xi;
    ldc(x + 2, cn);   // prefetch next column (independent)
    float acc = 0.f;
#pragma unroll
    for (int dy = 0; dy < 3; ++dy) {
      acc = fmaf(wt[dy * 3 + 0], c0[dy], acc);
      acc = fmaf(wt[dy * 3 + 1], c1[dy], acc);
      acc = fmaf(wt[dy * 3 + 2], c2[dy], acc);
    }
    float s = acc, sq = acc * acc;
#pragma unroll
    for (int off = 32; off > 0; off >>= 1) {
      s  += __shfl_xor(s, off);
      sq += __shfl_xor(sq, off);
    }
    const float mean = s * (1.f / 64.f);
    const float var  = sq * (1.f / 64.f) - mean * mean;
    const float rstd = rsqrtf(var + 1e-5f);
    qf[((size_t)bh * NQ + y * WW + x) * HD + lane] =
        (__bf16)((acc - mean) * rstd * gl + bl);
#pragma unroll
    for (int dy = 0; dy < 3; ++dy) {
      c0[dy] = c1[dy]; c1[dy] = c2[dy]; c2[dy] = cn[dy];
    }
  }
}

// ---------------- sr: depthwise 3x3 s2 p1 (+bias) + LN(768), bf16 in/out ----
__global__ __launch_bounds__(256) void sr_ln_kernel(
    const __bf16* __restrict__ x, const float* __restrict__ srt,
    const float* __restrict__ srb, const float* __restrict__ g,
    const float* __restrict__ bb, __bf16* __restrict__ out)
{
  const int row = xcd_swizzle(blockIdx.x, gridDim.x);   // b*784 + ns
  const int b = row / NS, ns = row - b * NS;
  const int ys = ns / WSS, xs = ns - ys * WSS;
  const int t = threadIdx.x;

  float fm[9];
  size_t off9[9];
#pragma unroll
  for (int tap = 0; tap < 9; ++tap) {
    const int yy = 2 * ys - 1 + tap / 3;
    const int xx = 2 * xs - 1 + tap % 3;
    fm[tap] = (yy >= 0 && yy < HH && xx >= 0 && xx < WW) ? 1.f : 0.f;
    const int yyc = min(max(yy, 0), HH - 1);
    const int xxc = min(max(xx, 0), WW - 1);
    off9[tap] = ((size_t)b * NQ + yyc * WW + xxc) * DIM;
  }

  float vals[3];
  float lsum = 0.f, lsq = 0.f;
#pragma unroll
  for (int i = 0; i < 3; ++i) {
    const int c = t + i * 256;
    float v9[9];
#pragma unroll
    for (int tap = 0; tap < 9; ++tap) v9[tap] = (float)x[off9[tap] + c];
    float acc = srb[c];
#pragma unroll
    for (int tap = 0; tap < 9; ++tap)
      acc = fmaf(srt[tap * DIM + c] * fm[tap], v9[tap], acc);
    vals[i] = acc;
    lsum += acc;
    lsq = fmaf(acc, acc, lsq);
  }
#pragma unroll
  for (int off = 32; off > 0; off >>= 1) {
    lsum += __shfl_xor(lsum, off);
    lsq  += __shfl_xor(lsq, off);
  }
  __shared__ float s1[4], s2[4];
  if ((t & 63) == 0) { s1[t >> 6] = lsum; s2[t >> 6] = lsq; }
  __syncthreads();
  const float S  = s1[0] + s1[1] + s1[2] + s1[3];
  const float SQ = s2[0] + s2[1] + s2[2] + s2[3];
  const float mean = S * (1.f / 768.f);
  const float var  = SQ * (1.f / 768.f) - mean * mean;
  const float rstd = rsqrtf(var + 1e-6f);
#pragma unroll
  for (int i = 0; i < 3; ++i) {
    const int c = t + i * 256;
    out[(size_t)row * DIM + c] = (__bf16)((vals[i] - mean) * rstd * g[c] + bb[c]);
  }
}

// ---------------- pool_k + pool_v merged: conv s2 + LN(64) ------------------
// y==0: K -> kpb[bh][nk][lane^((nk&7)<<3)]       (XOR-swizzled rows, 128B)
// y==1: V -> vtb[bh][lane][nk^((lane&7)<<3)]     (transposed, VSTR rows)
__global__ __launch_bounds__(256) void pool_kv_ln_kernel(
    const __bf16* __restrict__ kv, const float* __restrict__ pkw,
    const float* __restrict__ pvw, const float* __restrict__ kg,
    const float* __restrict__ kbb, const float* __restrict__ vg,
    const float* __restrict__ vbb, __bf16* __restrict__ kpb,
    __bf16* __restrict__ vtb)
{
  const int isv = blockIdx.y;
  const float* pw = isv ? pvw : pkw;
  const float* g  = isv ? vg  : kg;
  const float* bb = isv ? vbb : kbb;
  const int coloff = isv ? DIM : 0;

  const int lane = threadIdx.x & 63;
  const int r = blockIdx.x * 4 + (threadIdx.x >> 6);   // bh*224 + nk
  const int bh = r / NKP;
  const int nk = r - bh * NKP;

  float val = 0.f;
  if (nk < NKK) {
    const int b = bh / NHD, h = bh - b * NHD;
    const int yk = nk / WK, xk = nk - yk * WK;
    float acc = 0.f;
#pragma unroll
    for (int dy = 0; dy < 3; ++dy) {
      const int yy = 2 * yk - 1 + dy;
      if (yy < 0 || yy >= HS) continue;
#pragma unroll
      for (int dx = 0; dx < 3; ++dx) {
        const int xx = 2 * xk - 1 + dx;
        if (xx < 0 || xx >= WSS) continue;
        acc = fmaf(pw[lane * 9 + dy * 3 + dx],
                   (float)kv[((size_t)b * NS + yy * WSS + xx) * (2 * DIM) + coloff + h * HD + lane], acc);
      }
    }
    float s = acc, sq = acc * acc;
#pragma unroll
    for (int off = 32; off > 0; off >>= 1) {
      s  += __shfl_xor(s, off);
      sq += __shfl_xor(sq, off);
    }
    const float mean = s * (1.f / 64.f);
    const float var  = sq * (1.f / 64.f) - mean * mean;
    const float rstd = rsqrtf(var + 1e-5f);
    val = (acc - mean) * rstd * g[lane] + bb[lane];
  }
  if (!isv) {
    kpb[(size_t)bh * NKP * HD + nk * HD + (lane ^ ((nk & 7) << 3))] = (__bf16)val;
  } else {
    vtb[(size_t)bh * HD * VSTR + lane * VSTR + (nk ^ ((lane & 7) << 3))] = (__bf16)val;
  }
}

// ---------------- MFMA attention core ---------------------------------------
// ONE 32KB LDS region: K staged (gload_lds) -> QK (swapped: D[key][q]) ->
// barrier -> V staged into SAME region (latency hidden under softmax) ->
// softmax + P packed to bf16 dwords in REGISTERS -> PV with A-fragments
// redistributed via __shfl (compile-time pk indices only). No-max softmax.
__global__ __launch_bounds__(256) void attn_mfma_kernel(
    const __bf16* __restrict__ qf, const __bf16* __restrict__ kpb,
    const __bf16* __restrict__ vtb, __bf16* __restrict__ out)
{
  __shared__ __bf16 kv_lds[16384];   // 32,768 B: K (28,672B) then V (32,768B)
  const int bh = blockIdx.y;
  const int qt = blockIdx.x;
  const int t = threadIdx.x;
  const int lane = t & 63, w = t >> 6;
  const int fr = lane & 15;   // fragment row (key row in QK; q/d row in PV)
  const int fg = lane >> 4;   // k-chunk group
  const int q0 = qt * 64 + w * 16;
  const int sw = (fr & 7) << 4;   // XOR swizzle key (byte)

  // q loads (regs) — issued before staging, drained by the first barrier
  const __bf16* qbase = qf + ((size_t)bh * NQ + q0) * HD;
  const bf16x8 aq0 = *(const bf16x8*)(qbase + fr * HD + fg * 8);
  const bf16x8 aq1 = *(const bf16x8*)(qbase + fr * HD + 32 + fg * 8);

  // stage K (7x16B/thread), all independent
  char* kl = (char*)kv_lds;
  {
    const __bf16* kgp = kpb + (size_t)bh * (NKP * HD);
#pragma unroll
    for (int i = 0; i < 7; ++i)
      gload_lds16(kgp + (i * 256 + w * 64 + lane) * 8, kl + i * 4096 + w * 1024);
  }
  __syncthreads();   // K in LDS; q in regs

  // QK^T from LDS — SWAPPED operands: D[key][q]
  f32x4 s[13];
#pragma unroll
  for (int n = 0; n < 13; ++n) {
    const int rowb = (n * 16 + fr) << 7;   // 128B K rows
    const bf16x8 b0 = *(const bf16x8*)(kl + rowb + ((fg << 4) ^ sw));
    const bf16x8 b1 = *(const bf16x8*)(kl + rowb + (((fg << 4) + 64) ^ sw));
    f32x4 c = (f32x4){0.f, 0.f, 0.f, 0.f};
    c = __builtin_amdgcn_mfma_f32_16x16x32_bf16(b0, aq0, c, 0, 0, 0);
    c = __builtin_amdgcn_mfma_f32_16x16x32_bf16(b1, aq1, c, 0, 0, 0);
    s[n] = c;   // lane: keys n*16 + 4*fg + r (r=0..3), q-col = fr
  }
  __syncthreads();   // all waves done reading K; region becomes V

  // stage V (8x16B/thread) into the SAME region — latency hides under softmax
  {
    const __bf16* vgp = vtb + (size_t)bh * (HD * VSTR);
#pragma unroll
    for (int i = 0; i < 8; ++i)
      gload_lds16(vgp + (i * 256 + w * 64 + lane) * 8, kl + i * 4096 + w * 1024);
  }

  // softmax (no max): exp per score, P packed to bf16 dwords in registers
  const float scale = 0.125f;
  unsigned pk[28];
  float sum = 0.f;
#pragma unroll
  for (int n = 0; n < 13; ++n) {
    float e0 = __expf(s[n][0] * scale);
    float e1 = __expf(s[n][1] * scale);
    float e2 = __expf(s[n][2] * scale);
    float e3 = __expf(s[n][3] * scale);
    if (n == 12 && fg >= 1) { e0 = e1 = e2 = e3 = 0.f; }   // keys >=196 invalid
    sum += (e0 + e1) + (e2 + e3);
    pk[2 * n]     = pack_bf2(e0, e1);
    pk[2 * n + 1] = pack_bf2(e2, e3);
  }
  pk[26] = 0u; pk[27] = 0u;   // keys 208..223
  sum += __shfl_xor(sum, 16);
  sum += __shfl_xor(sum, 32);
  const float pinvL = 1.f / sum;   // 1/sum for q-row fr (all fg agree)

  __syncthreads();   // V ready in LDS

  // PV: A-fragment (P) redistributed via shfl; V from LDS.
  const int L1 = ((fg & 1) << 5) | fr;
  const int L2 = L1 + 16;
  const bool hi = (fg >= 2);
  f32x4 acc2[4];
#pragma unroll
  for (int dt = 0; dt < 4; ++dt) acc2[dt] = (f32x4){0.f, 0.f, 0.f, 0.f};
  const char* vl = (const char*)kv_lds;
#pragma unroll
  for (int ks = 0; ks < 7; ++ks) {
    const unsigned d0a = __shfl(pk[4 * ks + 0], L1), d0b = __shfl(pk[4 * ks + 2], L1);
    const unsigned d1a = __shfl(pk[4 * ks + 1], L1), d1b = __shfl(pk[4 * ks + 3], L1);
    const unsigned d2a = __shfl(pk[4 * ks + 0], L2), d2b = __shfl(pk[4 * ks + 2], L2);
    const unsigned d3a = __shfl(pk[4 * ks + 1], L2), d3b = __shfl(pk[4 * ks + 3], L2);
    uint4 pu;
    pu.x = hi ? d0b : d0a;
    pu.y = hi ? d1b : d1a;
    pu.z = hi ? d2b : d2a;
    pu.w = hi ? d3b : d3a;
    const bf16x8 pabf = __builtin_bit_cast(bf16x8, pu);
#pragma unroll
    for (int dt = 0; dt < 4; ++dt) {
      const bf16x8 bv = *(const bf16x8*)(vl + (dt * 16 + fr) * (VSTR * 2) + ((ks * 64 + (fg << 4)) ^ sw));
      acc2[dt] = __builtin_amdgcn_mfma_f32_16x16x32_bf16(pabf, bv, acc2[dt], 0, 0, 0);
    }
  }

  // epilogue: out row q = q0 + 4*fg + r, col d = dt*16 + fr.
  float pr[4];
#pragma unroll
  for (int r = 0; r < 4; ++r)
    pr[r] = __shfl(pinvL, (fg << 4) | (fg * 4 + r));
  const int b = bh / NHD, h = bh - b * NHD;
#pragma unroll
  for (int dt = 0; dt < 4; ++dt)
#pragma unroll
    for (int r = 0; r < 4; ++r)
      out[((size_t)b * NQ + q0 + 4 * fg + r) * DIM + h * HD + dt * 16 + fr] =
          (__bf16)(acc2[dt][r] * pr[r]);
}

// ---------------- identity path + add + LN -> bf16 proj input ---------------
#define XCH 2    // strips per ys row

__global__ __launch_bounds__(256) void idn_add_ln_kernel(
    const __bf16* __restrict__ kv, const float* __restrict__ upt,
    const float* __restrict__ upb, const float* __restrict__ g,
    const float* __restrict__ bb, const __bf16* __restrict__ io,
    __bf16* __restrict__ pj)
{
  int idx = xcd_swizzle(blockIdx.x, gridDim.x);
  const int chunk = idx & (XCH - 1); idx >>= 1;
  const int ys = idx % HS; idx /= HS;
  const int sidx = idx & 3;
  const int b = idx >> 2;
  const int sy = sidx >> 1, sx = sidx & 1;
  const int y = 2 * ys + sy;
  const int t = threadIdx.x;
  const int w = t >> 6;

  float wreg[3][9], ubias[3], gg[3], gb[3];
#pragma unroll
  for (int i = 0; i < 3; ++i) {
    const int c = t + i * 256;
    ubias[i] = upb[c * 4 + sidx];
    gg[i] = g[c];
    gb[i] = bb[c];
#pragma unroll
    for (int tap = 0; tap < 9; ++tap) {
      const int yy = ys - 1 + tap / 3;
      const float f = (yy >= 0 && yy < HS) ? 1.f : 0.f;   // fold row-OOB into weight
      wreg[i][tap] = upt[(sidx * 9 + tap) * DIM + c] * f;  // coalesced
    }
  }

  __shared__ __bf16 vals_lds[14][DIM];   // 21,504 B
  __shared__ float s1[14][4], s2[14][4];
  const int xs0 = chunk * 14;

  // clamped row indices (row-OOB contributes 0 via zeroed weights)
  const int y0 = max(ys - 1, 0), y1 = ys, y2 = min(ys + 1, HS - 1);
  const __bf16* vb0 = kv + ((size_t)(b * NS + y0 * WSS)) * (2 * DIM) + DIM + t;
  const __bf16* vb1 = kv + ((size_t)(b * NS + y1 * WSS)) * (2 * DIM) + DIM + t;
  const __bf16* vb2 = kv + ((size_t)(b * NS + y2 * WSS)) * (2 * DIM) + DIM + t;

  // unconditional clamped column load, col-OOB masked by multiply
  auto ldcol = [&](int ch, int p, float* dst) {
    const float m = (p >= 0 && p < WSS) ? 1.f : 0.f;
    const int xx = min(max(p, 0), WSS - 1);
    const size_t off = (size_t)xx * (2 * DIM) + ch * 256;
    dst[0] = m * (float)vb0[off];
    dst[1] = m * (float)vb1[off];
    dst[2] = m * (float)vb2[off];
  };

  float c0[3][3], c1[3][3], c2[3][3], cn[3][3];
#pragma unroll
  for (int ch = 0; ch < 3; ++ch) {
    ldcol(ch, xs0 - 1, c0[ch]);
    ldcol(ch, xs0,     c1[ch]);
    ldcol(ch, xs0 + 1, c2[ch]);
  }

#pragma unroll
  for (int xi = 0; xi < 14; ++xi) {
    const int xs = xs0 + xi;
#pragma unroll
    for (int ch = 0; ch < 3; ++ch) ldcol(ch, xs + 2, cn[ch]);
    float lsum = 0.f, lsq = 0.f;
#pragma unroll
    for (int ch = 0; ch < 3; ++ch) {
      float acc = ubias[ch];
#pragma unroll
      for (int dy = 0; dy < 3; ++dy) {
        acc = fmaf(wreg[ch][dy * 3 + 0], c0[ch][dy], acc);
        acc = fmaf(wreg[ch][dy * 3 + 1], c1[ch][dy], acc);
        acc = fmaf(wreg[ch][dy * 3 + 2], c2[ch][dy], acc);
      }
      vals_lds[xi][t + ch * 256] = (__bf16)acc;
      lsum += acc;
      lsq = fmaf(acc, acc, lsq);
    }
#pragma unroll
    for (int off = 32; off > 0; off >>= 1) {
      lsum += __shfl_xor(lsum, off);
      lsq  += __shfl_xor(lsq, off);
    }
    if ((t & 63) == 0) { s1[xi][w] = lsum; s2[xi][w] = lsq; }
#pragma unroll
    for (int ch = 0; ch < 3; ++ch)
#pragma unroll
      for (int dy = 0; dy < 3; ++dy) {
        c0[ch][dy] = c1[ch][dy];
        c1[ch][dy] = c2[ch][dy];
        c2[ch][dy] = cn[ch][dy];
      }
  }
  __syncthreads();   // ONE barrier: all conv values + partials in LDS

#pragma unroll
  for (int xi = 0; xi < 14; ++xi) {
    const float S  = s1[xi][0] + s1[xi][1] + s1[xi][2] + s1[xi][3];
    const float SQ = s2[xi][0] + s2[xi][1] + s2[xi][2] + s2[xi][3];
    const float mean = S * (1.f / 768.f);
    const float var  = SQ * (1.f / 768.f) - mean * mean;
    const float rstd = rsqrtf(var + 1e-6f);
    const int x = 2 * (xs0 + xi) + sx;
    const size_t row = (size_t)b * NQ + y * WW + x;
#pragma unroll
    for (int ch = 0; ch < 3; ++ch) {
      const int c = t + ch * 256;
      pj[row * DIM + c] =
          (__bf16)((float)io[row * DIM + c] +
                   ((float)vals_lds[xi][c] - mean) * rstd * gg[ch] + gb[ch]);
    }
  }
}

// =============================================================================
extern "C" void kernel_launch(void* const* d_in, const int* in_sizes, int n_in,
                              void* d_out, int out_size, void* d_ws, size_t ws_size,
                              hipStream_t stream)
{
  const float* x      = (const float*)d_in[0];
  const float* q_w    = (const float*)d_in[1];
  const float* q_b    = (const float*)d_in[2];
  const float* kv_w   = (const float*)d_in[3];
  const float* kv_b   = (const float*)d_in[4];
  const float* sr_w   = (const float*)d_in[5];
  const float* sr_b   = (const float*)d_in[6];
  const float* srn_g  = (const float*)d_in[7];
  const float* srn_b  = (const float*)d_in[8];
  const float* up_w   = (const float*)d_in[9];
  const float* up_b   = (const float*)d_in[10];
  const float* upn_g  = (const float*)d_in[11];
  const float* upn_b  = (const float*)d_in[12];
  const float* proj_w = (const float*)d_in[13];
  const float* proj_b = (const float*)d_in[14];
  const float* pq_w   = (const float*)d_in[15];
  const float* pk_w   = (const float*)d_in[16];
  const float* pv_w   = (const float*)d_in[17];
  const float* nq_g   = (const float*)d_in[18];
  const float* nq_b   = (const float*)d_in[19];
  const float* nk_g   = (const float*)d_in[20];
  const float* nk_b   = (const float*)d_in[21];
  const float* nv_g   = (const float*)d_in[22];
  const float* nv_b   = (const float*)d_in[23];

  const int B = in_sizes[0] / (NQ * DIM);   // 8
  const int M1 = B * NQ;                    // 25088
  const int M2 = B * NS;                    // 6272

  // workspace layout (bytes)
  char* p = (char*)d_ws;
  __bf16* xb    = (__bf16*)p;  p += (size_t)M1 * DIM * 2;        // x bf16; reused as pjin
  float*  qproj = (float*)p;   p += (size_t)M1 * DIM * 4;        // qp bf16 / attnout bf16
  __bf16* qf    = (__bf16*)p;  p += (size_t)M1 * DIM * 2;        // pooled+LN q (bf16)
  __bf16* xsln  = (__bf16*)p;  p += (size_t)M2 * DIM * 2;        // sr+LN out (bf16)
  __bf16* kvb   = (__bf16*)p;  p += (size_t)M2 * 2 * DIM * 2;    // kv-proj out (bf16)
  __bf16* kpb   = (__bf16*)p;  p += (size_t)B * NHD * NKP * HD * 2;   // pooled k, swizzled
  __bf16* vtb   = (__bf16*)p;  p += (size_t)B * NHD * HD * VSTR * 2;  // pooled v, transposed+swizzled
  __bf16* wqt   = (__bf16*)p;  p += (size_t)DIM * DIM * 2;       // q_w^T bf16 [N][K]
  __bf16* wkvt  = (__bf16*)p;  p += (size_t)DIM * 2 * DIM * 2;   // kv_w^T bf16
  __bf16* wpjt  = (__bf16*)p;  p += (size_t)DIM * DIM * 2;       // proj_w^T bf16
  float*  upt   = (float*)p;   p += (size_t)4 * 9 * DIM * 4;     // up_w transposed [sidx][tap][c]
  float*  srt   = (float*)p;   p += (size_t)9 * DIM * 4;         // sr_w transposed [tap][c]
  __bf16* qp      = (__bf16*)qproj;  // bf16 permuted q-proj (dead before attnout live)
  __bf16* attnout = (__bf16*)qproj;  // bf16 attention output (after qp dead)
  __bf16* pjin    = xb;

  dim3 blk(256);

  // 0. casts / weight transposes (merged: 3 dispatches)
  cast_bf16_kernel<<<2048, blk, 0, stream>>>(x, xb, (long)M1 * DIM / 4);
  wt3_cast_kernel<<<dim3(48, 24, 3), blk, 0, stream>>>(
      q_w, kv_w, proj_w, wqt, wkvt, wpjt);
  misc_tr_kernel<<<(5 * 9 * DIM + 255) / 256, blk, 0, stream>>>(
      up_w, upt, sr_w, srt);

  // 1. q projection (bf16 MFMA, triple-buf counted-vmcnt) -> qp bf16 permuted
  gemm_mfma_kernel<1><<<(M1 / 128) * (DIM / 128), blk, 0, stream>>>(
      xb, wqt, q_b, nullptr, qp, M1, DIM, DIM);

  // 2. pool_q conv + LN(64) -> bf16 (sliding-window, unconditional loads)
  pool_q_ln_kernel<<<B * NHD * HH, blk, 0, stream>>>(
      qp, pq_w, nq_g, nq_b, qf);

  // 3. spatial reduction conv + LN(768) -> bf16 (unconditional loads)
  sr_ln_kernel<<<B * NS, blk, 0, stream>>>(
      xb, srt, sr_b, srn_g, srn_b, xsln);

  // 4. kv projection (bf16 MFMA) -> bf16 row-major
  gemm_mfma_kernel<2><<<(M2 / 128) * (2 * DIM / 128), blk, 0, stream>>>(
      xsln, wkvt, kv_b, nullptr, kvb, M2, 2 * DIM, DIM);

  // 5. pool k (swizzled [bh][224][64]) and v (transposed+swizzled [bh][64][256])
  pool_kv_ln_kernel<<<dim3((B * NHD * NKP) / 4, 2), blk, 0, stream>>>(
      kvb, pk_w, pv_w, nk_g, nk_b, nv_g, nv_b, kpb, vtb);

  // 6. MFMA attention core -> attnout (bf16; 32KB LDS, P in registers)
  attn_mfma_kernel<<<dim3(NQ / 64, B * NHD), blk, 0, stream>>>(
      qf, kpb, vtb, attnout);

  // 7. identity path + add -> bf16 proj input (reuses xb region)
  idn_add_ln_kernel<<<B * 4 * HS * XCH, blk, 0, stream>>>(
      kvb, upt, up_b, upn_g, upn_b, attnout, pjin);

  // 8. output projection (bf16 MFMA) -> d_out (f32, nontemporal)
  gemm_mfma_kernel<0><<<(M1 / 128) * (DIM / 128), blk, 0, stream>>>(
      pjin, wpjt, proj_b, (float*)d_out, nullptr, M1, DIM, DIM);
}

// Round 20
// 317.844 us; speedup vs baseline: 1.0567x; 1.0025x over previous
//
#include <hip/hip_runtime.h>
#include <cstdint>
#include <cstddef>

#define DIM 768
#define NHD 12
#define HD  64
#define HH  56
#define WW  56
#define NQ  3136   // 56*56
#define HS  28
#define WSS 28
#define NS  784    // 28*28
#define HK  14
#define WK  14
#define NKK 196    // 14*14
#define NKP 224    // keys padded to 7*32 for PV k-loop
#define VSTR 256   // v row stride in bf16 (512B rows -> complete 128B XOR blocks)

typedef __bf16 bf16x8 __attribute__((ext_vector_type(8)));
typedef __bf16 bf16x4 __attribute__((ext_vector_type(4)));
typedef float  f32x4  __attribute__((ext_vector_type(4)));

// ---------------------------------------------------------------------------
// bijective XCD-aware block swizzle (m204)
__device__ __forceinline__ int xcd_swizzle(int bid, int nwg) {
  const int q = nwg >> 3, r = nwg & 7;
  const int xcd = bid & 7, off = bid >> 3;
  return (xcd < r ? xcd * (q + 1) : r * (q + 1) + (xcd - r) * q) + off;
}

// async global->LDS 16B copy (dest = wave-uniform base + lane*16)
__device__ __forceinline__ void gload_lds16(const void* g, void* l) {
  __builtin_amdgcn_global_load_lds(
      (const __attribute__((address_space(1))) void*)g,
      (__attribute__((address_space(3))) void*)l, 16, 0, 0);
}

__device__ __forceinline__ unsigned pack_bf2(float a, float b) {
  union { __bf16 h; unsigned short u; } lo, hi;
  lo.h = (__bf16)a; hi.h = (__bf16)b;
  return (unsigned)lo.u | ((unsigned)hi.u << 16);
}

// ---------------- bf16 MFMA GEMM: C[M,N] = A[M,K] @ Bt[N,K]^T + bias --------
// 128x128 tile, 4 waves, TRIPLE-buffered global_load_lds with COUNTED vmcnt
// + raw s_barrier (T4): the barrier never drains the in-flight prefetch.
// Per K-step: s_waitcnt vmcnt(4) -> s_barrier -> issue kt+2's 4 loads ->
// ds_read + 16 MFMA. Chunk-XOR both-sides swizzle (conflict-free, r15).
// MODE 0: C f32 row-major. MODE 1: Cq bf16 permuted [b][h][n][hd] (q-proj).
// MODE 2: Cq bf16 row-major.
template<int MODE>
__global__ __launch_bounds__(256) void gemm_mfma_kernel(
    const __bf16* __restrict__ A, const __bf16* __restrict__ Bt,
    const float* __restrict__ bias, float* __restrict__ C,
    __bf16* __restrict__ Cq, int M, int N, int K)
{
  __shared__ __bf16 As[3][128 * 32];   // 3 x 8 KB
  __shared__ __bf16 Bs[3][128 * 32];   // 3 x 8 KB (48 KB total)

  const int nX = N >> 7;
  const int bid = xcd_swizzle(blockIdx.x, (M >> 7) * nX);
  const int row0 = (bid / nX) << 7;
  const int col0 = (bid % nX) << 7;

  const int t = threadIdx.x;
  const int lane = t & 63;
  const int w = t >> 6;                 // wave 0..3
  const int wr = w >> 1, wc = w & 1;    // 2x2 wave grid
  const int fr = lane & 15;
  const int fc = lane >> 4;

  // staging: thread t covers rows r0 = t>>2 and r0+64, chunk ch = t&3;
  // source chunk pre-swizzled sc = ch ^ ((r0>>1)&3). LDS dest LINEAR.
  const int r0 = t >> 2;
  const int ch = t & 3;
  const int sc = ch ^ ((r0 >> 1) & 3);
  const __bf16* Ap0 = A + (size_t)(row0 + r0) * K + sc * 8;
  const __bf16* Ap1 = A + (size_t)(row0 + r0 + 64) * K + sc * 8;
  const __bf16* Bp0 = Bt + (size_t)(col0 + r0) * K + sc * 8;
  const __bf16* Bp1 = Bt + (size_t)(col0 + r0 + 64) * K + sc * 8;
  char* Asb = (char*)As;
  char* Bsb = (char*)Bs;
  const int db = w * 1024;

  f32x4 acc[4][4];
#pragma unroll
  for (int i = 0; i < 4; ++i)
#pragma unroll
    for (int j = 0; j < 4; ++j) acc[i][j] = (f32x4){0.f, 0.f, 0.f, 0.f};

  const int keyA = (fr >> 1) & 3;   // fragment-read XOR key (row-derived)

  const int NT = K >> 5;   // K/32 (>= 2 for all our shapes)

  // prologue: stage tiles 0 and 1 into buffers 0 and 1 (8 loads in flight)
  gload_lds16(Ap0, Asb + db);
  gload_lds16(Ap1, Asb + 4096 + db);
  gload_lds16(Bp0, Bsb + db);
  gload_lds16(Bp1, Bsb + 4096 + db);
  {
    const int ko = 1 << 5;
    gload_lds16(Ap0 + ko, Asb + 8192 + db);
    gload_lds16(Ap1 + ko, Asb + 8192 + 4096 + db);
    gload_lds16(Bp0 + ko, Bsb + 8192 + db);
    gload_lds16(Bp1 + ko, Bsb + 8192 + 4096 + db);
  }

  int bcur = 0;        // buffer holding tile kt
  for (int kt = 0; kt < NT; ++kt) {
    // own oldest loads (this tile's) retired; keep next tile's in flight
    if (kt + 1 < NT) {
      asm volatile("s_waitcnt vmcnt(4)" ::: "memory");
    } else {
      asm volatile("s_waitcnt vmcnt(0)" ::: "memory");
    }
    __builtin_amdgcn_s_barrier();   // publish: all waves' tile-kt loads done

    if (kt + 2 < NT) {   // issue tile kt+2 into the buffer read at kt-1
      const int ko = (kt + 2) << 5;
      const int ob = ((bcur + 2) % 3) * 8192;
      gload_lds16(Ap0 + ko, Asb + ob + db);
      gload_lds16(Ap1 + ko, Asb + ob + 4096 + db);
      gload_lds16(Bp0 + ko, Bsb + ob + db);
      gload_lds16(Bp1 + ko, Bsb + ob + 4096 + db);
    }

    const char* Ab = Asb + bcur * 8192;
    const char* Bb = Bsb + bcur * 8192;
    bf16x8 af[4], bfr[4];
#pragma unroll
    for (int i = 0; i < 4; ++i) {
      const int r = wr * 64 + i * 16 + fr;
      af[i] = *(const bf16x8*)(Ab + r * 64 + ((fc ^ keyA) << 4));
    }
#pragma unroll
    for (int j = 0; j < 4; ++j) {
      const int r = wc * 64 + j * 16 + fr;
      bfr[j] = *(const bf16x8*)(Bb + r * 64 + ((fc ^ keyA) << 4));
    }
#pragma unroll
    for (int i = 0; i < 4; ++i)
#pragma unroll
      for (int j = 0; j < 4; ++j)
        acc[i][j] = __builtin_amdgcn_mfma_f32_16x16x32_bf16(af[i], bfr[j], acc[i][j], 0, 0, 0);

    bcur = (bcur == 2) ? 0 : bcur + 1;
  }

  const int orow = row0 + wr * 64 + ((lane >> 4) << 2);
  const int ocol = col0 + wc * 64 + (lane & 15);
#pragma unroll
  for (int j = 0; j < 4; ++j) {
    const int col = ocol + j * 16;
    const float bv = bias[col];
#pragma unroll
    for (int i = 0; i < 4; ++i)
#pragma unroll
      for (int r = 0; r < 4; ++r) {
        const int rrow = orow + i * 16 + r;
        if (MODE == 0) {
          C[(size_t)rrow * N + col] = acc[i][j][r] + bv;
        } else if (MODE == 1) {
          const int b = rrow / NQ, n = rrow - b * NQ;
          const int h = col >> 6, hd = col & 63;
          Cq[(((size_t)b * NHD + h) * NQ + n) * HD + hd] = (__bf16)(acc[i][j][r] + bv);
        } else {
          Cq[(size_t)rrow * N + col] = (__bf16)(acc[i][j][r] + bv);
        }
      }
  }
}

// ---------------- f32 -> bf16 cast (vectorized, grid-stride) ----------------
__global__ __launch_bounds__(256) void cast_bf16_kernel(
    const float* __restrict__ in, __bf16* __restrict__ out, long n4)
{
  long i = (long)blockIdx.x * 256 + threadIdx.x;
  const long stride = (long)gridDim.x * 256;
  for (; i < n4; i += stride) {
    float4 v = *(const float4*)(in + i * 4);
    bf16x4 o;
    o.x = (__bf16)v.x; o.y = (__bf16)v.y; o.z = (__bf16)v.z; o.w = (__bf16)v.w;
    *(bf16x4*)(out + i * 4) = o;
  }
}

// ---------------- merged weight transpose+cast for q_w / kv_w / proj_w -----
__global__ __launch_bounds__(256) void wt3_cast_kernel(
    const float* __restrict__ q_w, const float* __restrict__ kv_w,
    const float* __restrict__ proj_w, __bf16* __restrict__ wqt,
    __bf16* __restrict__ wkvt, __bf16* __restrict__ wpjt)
{
  const int which = blockIdx.z;
  const float* W = (which == 0) ? q_w : (which == 1) ? kv_w : proj_w;
  __bf16* Wt = (which == 0) ? wqt : (which == 1) ? wkvt : wpjt;
  const int N = (which == 1) ? 2 * DIM : DIM;
  const int n0 = blockIdx.x << 5;
  if (n0 >= N) return;
  const int k0 = blockIdx.y << 5;
  __shared__ float tile[32][33];
  const int tc = threadIdx.x & 31;
  const int tr = threadIdx.x >> 5;   // 0..7
#pragma unroll
  for (int i = 0; i < 4; ++i)
    tile[tr + i * 8][tc] = W[(size_t)(k0 + tr + i * 8) * N + n0 + tc];
  __syncthreads();
#pragma unroll
  for (int i = 0; i < 4; ++i)
    Wt[(size_t)(n0 + tr + i * 8) * DIM + k0 + tc] = (__bf16)tile[tc][tr + i * 8];
}

// ---------------- merged small transposes: up_w -> upt, sr_w -> srt ---------
__global__ __launch_bounds__(256) void misc_tr_kernel(
    const float* __restrict__ upw, float* __restrict__ upt,
    const float* __restrict__ srw, float* __restrict__ srt)
{
  const int i = blockIdx.x * 256 + threadIdx.x;
  if (i < 4 * 9 * DIM) {
    const int c = i % DIM;
    const int rest = i / DIM;
    const int tap = rest % 9, sidx = rest / 9;
    upt[i] = upw[(c * 4 + sidx) * 9 + tap];
  } else {
    const int j = i - 4 * 9 * DIM;
    if (j < 9 * DIM) {
      const int c = j % DIM;
      const int tap = j / DIM;
      srt[j] = srw[c * 9 + tap];
    }
  }
}

// ---------------- pool_q: depthwise 3x3 s1 p1 + LN(64) -----------------------
__global__ __launch_bounds__(256) void pool_q_ln_kernel(
    const __bf16* __restrict__ qp, const float* __restrict__ pqw,
    const float* __restrict__ g, const float* __restrict__ bb,
    __bf16* __restrict__ qf)
{
  const int blk = xcd_swizzle(blockIdx.x, gridDim.x);
  const int bh = blk / HH, y = blk - bh * HH;
  const int lane = threadIdx.x & 63;
  const int w = threadIdx.x >> 6;
  const int x0 = w * (WW / 4);   // 14-px strip

  float wt[9];
#pragma unroll
  for (int tap = 0; tap < 9; ++tap) {
    const int yy = y - 1 + tap / 3;
    wt[tap] = (yy >= 0 && yy < HH) ? pqw[lane * 9 + tap] : 0.f;
  }
  const float gl = g[lane], bl = bb[lane];

  const __bf16* rp0;
  const __bf16* rp1;
  const __bf16* rp2;
  {
    const __bf16* base = qp + (size_t)bh * NQ * HD + lane;
    rp0 = base + (size_t)min(max(y - 1, 0), HH - 1) * WW * HD;
    rp1 = base + (size_t)y * WW * HD;
    rp2 = base + (size_t)min(max(y + 1, 0), HH - 1) * WW * HD;
  }
  auto ldc = [&](int xx, float* d) {
    const float m = (xx >= 0 && xx < WW) ? 1.f : 0.f;
    const int xc = min(max(xx, 0), WW - 1);
    d[0] = m * (float)rp0[(size_t)xc * HD];
    d[1] = m * (float)rp1[(size_t)xc * HD];
    d[2] = m * (float)rp2[(size_t)xc * HD];
  };

  float c0[3], c1[3], c2[3], cn[3];
  ldc(x0 - 1, c0);
  ldc(x0,     c1);
  ldc(x0 + 1, c2);

#pragma unroll
  for (int xi = 0; xi < WW / 4; ++xi) {
    const int x = x0 + xi;
    ldc(x + 2, cn);   // prefetch next column (independent)
    float acc = 0.f;
#pragma unroll
    for (int dy = 0; dy < 3; ++dy) {
      acc = fmaf(wt[dy * 3 + 0], c0[dy], acc);
      acc = fmaf(wt[dy * 3 + 1], c1[dy], acc);
      acc = fmaf(wt[dy * 3 + 2], c2[dy], acc);
    }
    float s = acc, sq = acc * acc;
#pragma unroll
    for (int off = 32; off > 0; off >>= 1) {
      s  += __shfl_xor(s, off);
      sq += __shfl_xor(sq, off);
    }
    const float mean = s * (1.f / 64.f);
    const float var  = sq * (1.f / 64.f) - mean * mean;
    const float rstd = rsqrtf(var + 1e-5f);
    qf[((size_t)bh * NQ + y * WW + x) * HD + lane] =
        (__bf16)((acc - mean) * rstd * gl + bl);
#pragma unroll
    for (int dy = 0; dy < 3; ++dy) {
      c0[dy] = c1[dy]; c1[dy] = c2[dy]; c2[dy] = cn[dy];
    }
  }
}

// ---------------- sr: depthwise 3x3 s2 p1 (+bias) + LN(768), bf16 in/out ----
__global__ __launch_bounds__(256) void sr_ln_kernel(
    const __bf16* __restrict__ x, const float* __restrict__ srt,
    const float* __restrict__ srb, const float* __restrict__ g,
    const float* __restrict__ bb, __bf16* __restrict__ out)
{
  const int row = xcd_swizzle(blockIdx.x, gridDim.x);   // b*784 + ns
  const int b = row / NS, ns = row - b * NS;
  const int ys = ns / WSS, xs = ns - ys * WSS;
  const int t = threadIdx.x;

  float fm[9];
  size_t off9[9];
#pragma unroll
  for (int tap = 0; tap < 9; ++tap) {
    const int yy = 2 * ys - 1 + tap / 3;
    const int xx = 2 * xs - 1 + tap % 3;
    fm[tap] = (yy >= 0 && yy < HH && xx >= 0 && xx < WW) ? 1.f : 0.f;
    const int yyc = min(max(yy, 0), HH - 1);
    const int xxc = min(max(xx, 0), WW - 1);
    off9[tap] = ((size_t)b * NQ + yyc * WW + xxc) * DIM;
  }

  float vals[3];
  float lsum = 0.f, lsq = 0.f;
#pragma unroll
  for (int i = 0; i < 3; ++i) {
    const int c = t + i * 256;
    float v9[9];
#pragma unroll
    for (int tap = 0; tap < 9; ++tap) v9[tap] = (float)x[off9[tap] + c];
    float acc = srb[c];
#pragma unroll
    for (int tap = 0; tap < 9; ++tap)
      acc = fmaf(srt[tap * DIM + c] * fm[tap], v9[tap], acc);
    vals[i] = acc;
    lsum += acc;
    lsq = fmaf(acc, acc, lsq);
  }
#pragma unroll
  for (int off = 32; off > 0; off >>= 1) {
    lsum += __shfl_xor(lsum, off);
    lsq  += __shfl_xor(lsq, off);
  }
  __shared__ float s1[4], s2[4];
  if ((t & 63) == 0) { s1[t >> 6] = lsum; s2[t >> 6] = lsq; }
  __syncthreads();
  const float S  = s1[0] + s1[1] + s1[2] + s1[3];
  const float SQ = s2[0] + s2[1] + s2[2] + s2[3];
  const float mean = S * (1.f / 768.f);
  const float var  = SQ * (1.f / 768.f) - mean * mean;
  const float rstd = rsqrtf(var + 1e-6f);
#pragma unroll
  for (int i = 0; i < 3; ++i) {
    const int c = t + i * 256;
    out[(size_t)row * DIM + c] = (__bf16)((vals[i] - mean) * rstd * g[c] + bb[c]);
  }
}

// ---------------- pool_k + pool_v merged: conv s2 + LN(64) ------------------
// y==0: K -> kpb[bh][nk][lane^((nk&7)<<3)]       (XOR-swizzled rows, 128B)
// y==1: V -> vtb[bh][lane][nk^((lane&7)<<3)]     (transposed, VSTR rows)
__global__ __launch_bounds__(256) void pool_kv_ln_kernel(
    const __bf16* __restrict__ kv, const float* __restrict__ pkw,
    const float* __restrict__ pvw, const float* __restrict__ kg,
    const float* __restrict__ kbb, const float* __restrict__ vg,
    const float* __restrict__ vbb, __bf16* __restrict__ kpb,
    __bf16* __restrict__ vtb)
{
  const int isv = blockIdx.y;
  const float* pw = isv ? pvw : pkw;
  const float* g  = isv ? vg  : kg;
  const float* bb = isv ? vbb : kbb;
  const int coloff = isv ? DIM : 0;

  const int lane = threadIdx.x & 63;
  const int r = blockIdx.x * 4 + (threadIdx.x >> 6);   // bh*224 + nk
  const int bh = r / NKP;
  const int nk = r - bh * NKP;

  float val = 0.f;
  if (nk < NKK) {
    const int b = bh / NHD, h = bh - b * NHD;
    const int yk = nk / WK, xk = nk - yk * WK;
    float acc = 0.f;
#pragma unroll
    for (int dy = 0; dy < 3; ++dy) {
      const int yy = 2 * yk - 1 + dy;
      if (yy < 0 || yy >= HS) continue;
#pragma unroll
      for (int dx = 0; dx < 3; ++dx) {
        const int xx = 2 * xk - 1 + dx;
        if (xx < 0 || xx >= WSS) continue;
        acc = fmaf(pw[lane * 9 + dy * 3 + dx],
                   (float)kv[((size_t)b * NS + yy * WSS + xx) * (2 * DIM) + coloff + h * HD + lane], acc);
      }
    }
    float s = acc, sq = acc * acc;
#pragma unroll
    for (int off = 32; off > 0; off >>= 1) {
      s  += __shfl_xor(s, off);
      sq += __shfl_xor(sq, off);
    }
    const float mean = s * (1.f / 64.f);
    const float var  = sq * (1.f / 64.f) - mean * mean;
    const float rstd = rsqrtf(var + 1e-5f);
    val = (acc - mean) * rstd * g[lane] + bb[lane];
  }
  if (!isv) {
    kpb[(size_t)bh * NKP * HD + nk * HD + (lane ^ ((nk & 7) << 3))] = (__bf16)val;
  } else {
    vtb[(size_t)bh * HD * VSTR + lane * VSTR + (nk ^ ((lane & 7) << 3))] = (__bf16)val;
  }
}

// ---------------- MFMA attention core ---------------------------------------
// ONE 32KB LDS region: K staged (gload_lds) -> QK (swapped: D[key][q]) ->
// barrier -> V staged into SAME region (latency hidden under softmax) ->
// softmax + P packed to bf16 dwords in REGISTERS -> PV with A-fragments
// redistributed via __shfl (compile-time pk indices only). No-max softmax.
__global__ __launch_bounds__(256) void attn_mfma_kernel(
    const __bf16* __restrict__ qf, const __bf16* __restrict__ kpb,
    const __bf16* __restrict__ vtb, __bf16* __restrict__ out)
{
  __shared__ __bf16 kv_lds[16384];   // 32,768 B: K (28,672B) then V (32,768B)
  const int bh = blockIdx.y;
  const int qt = blockIdx.x;
  const int t = threadIdx.x;
  const int lane = t & 63, w = t >> 6;
  const int fr = lane & 15;   // fragment row (key row in QK; q/d row in PV)
  const int fg = lane >> 4;   // k-chunk group
  const int q0 = qt * 64 + w * 16;
  const int sw = (fr & 7) << 4;   // XOR swizzle key (byte)

  // q loads (regs) — issued before staging, drained by the first barrier
  const __bf16* qbase = qf + ((size_t)bh * NQ + q0) * HD;
  const bf16x8 aq0 = *(const bf16x8*)(qbase + fr * HD + fg * 8);
  const bf16x8 aq1 = *(const bf16x8*)(qbase + fr * HD + 32 + fg * 8);

  // stage K (7x16B/thread), all independent
  char* kl = (char*)kv_lds;
  {
    const __bf16* kgp = kpb + (size_t)bh * (NKP * HD);
#pragma unroll
    for (int i = 0; i < 7; ++i)
      gload_lds16(kgp + (i * 256 + w * 64 + lane) * 8, kl + i * 4096 + w * 1024);
  }
  __syncthreads();   // K in LDS; q in regs

  // QK^T from LDS — SWAPPED operands: D[key][q]
  f32x4 s[13];
#pragma unroll
  for (int n = 0; n < 13; ++n) {
    const int rowb = (n * 16 + fr) << 7;   // 128B K rows
    const bf16x8 b0 = *(const bf16x8*)(kl + rowb + ((fg << 4) ^ sw));
    const bf16x8 b1 = *(const bf16x8*)(kl + rowb + (((fg << 4) + 64) ^ sw));
    f32x4 c = (f32x4){0.f, 0.f, 0.f, 0.f};
    c = __builtin_amdgcn_mfma_f32_16x16x32_bf16(b0, aq0, c, 0, 0, 0);
    c = __builtin_amdgcn_mfma_f32_16x16x32_bf16(b1, aq1, c, 0, 0, 0);
    s[n] = c;   // lane: keys n*16 + 4*fg + r (r=0..3), q-col = fr
  }
  __syncthreads();   // all waves done reading K; region becomes V

  // stage V (8x16B/thread) into the SAME region — latency hides under softmax
  {
    const __bf16* vgp = vtb + (size_t)bh * (HD * VSTR);
#pragma unroll
    for (int i = 0; i < 8; ++i)
      gload_lds16(vgp + (i * 256 + w * 64 + lane) * 8, kl + i * 4096 + w * 1024);
  }

  // softmax (no max): exp per score, P packed to bf16 dwords in registers
  const float scale = 0.125f;
  unsigned pk[28];
  float sum = 0.f;
#pragma unroll
  for (int n = 0; n < 13; ++n) {
    float e0 = __expf(s[n][0] * scale);
    float e1 = __expf(s[n][1] * scale);
    float e2 = __expf(s[n][2] * scale);
    float e3 = __expf(s[n][3] * scale);
    if (n == 12 && fg >= 1) { e0 = e1 = e2 = e3 = 0.f; }   // keys >=196 invalid
    sum += (e0 + e1) + (e2 + e3);
    pk[2 * n]     = pack_bf2(e0, e1);
    pk[2 * n + 1] = pack_bf2(e2, e3);
  }
  pk[26] = 0u; pk[27] = 0u;   // keys 208..223
  sum += __shfl_xor(sum, 16);
  sum += __shfl_xor(sum, 32);
  const float pinvL = 1.f / sum;   // 1/sum for q-row fr (all fg agree)

  __syncthreads();   // V ready in LDS

  // PV: A-fragment (P) redistributed via shfl; V from LDS.
  const int L1 = ((fg & 1) << 5) | fr;
  const int L2 = L1 + 16;
  const bool hi = (fg >= 2);
  f32x4 acc2[4];
#pragma unroll
  for (int dt = 0; dt < 4; ++dt) acc2[dt] = (f32x4){0.f, 0.f, 0.f, 0.f};
  const char* vl = (const char*)kv_lds;
#pragma unroll
  for (int ks = 0; ks < 7; ++ks) {
    const unsigned d0a = __shfl(pk[4 * ks + 0], L1), d0b = __shfl(pk[4 * ks + 2], L1);
    const unsigned d1a = __shfl(pk[4 * ks + 1], L1), d1b = __shfl(pk[4 * ks + 3], L1);
    const unsigned d2a = __shfl(pk[4 * ks + 0], L2), d2b = __shfl(pk[4 * ks + 2], L2);
    const unsigned d3a = __shfl(pk[4 * ks + 1], L2), d3b = __shfl(pk[4 * ks + 3], L2);
    uint4 pu;
    pu.x = hi ? d0b : d0a;
    pu.y = hi ? d1b : d1a;
    pu.z = hi ? d2b : d2a;
    pu.w = hi ? d3b : d3a;
    const bf16x8 pabf = __builtin_bit_cast(bf16x8, pu);
#pragma unroll
    for (int dt = 0; dt < 4; ++dt) {
      const bf16x8 bv = *(const bf16x8*)(vl + (dt * 16 + fr) * (VSTR * 2) + ((ks * 64 + (fg << 4)) ^ sw));
      acc2[dt] = __builtin_amdgcn_mfma_f32_16x16x32_bf16(pabf, bv, acc2[dt], 0, 0, 0);
    }
  }

  // epilogue: out row q = q0 + 4*fg + r, col d = dt*16 + fr.
  float pr[4];
#pragma unroll
  for (int r = 0; r < 4; ++r)
    pr[r] = __shfl(pinvL, (fg << 4) | (fg * 4 + r));
  const int b = bh / NHD, h = bh - b * NHD;
#pragma unroll
  for (int dt = 0; dt < 4; ++dt)
#pragma unroll
    for (int r = 0; r < 4; ++r)
      out[((size_t)b * NQ + q0 + 4 * fg + r) * DIM + h * HD + dt * 16 + fr] =
          (__bf16)(acc2[dt][r] * pr[r]);
}

// ---------------- identity path + add + LN -> bf16 proj input ---------------
#define XCH 2    // strips per ys row

__global__ __launch_bounds__(256) void idn_add_ln_kernel(
    const __bf16* __restrict__ kv, const float* __restrict__ upt,
    const float* __restrict__ upb, const float* __restrict__ g,
    const float* __restrict__ bb, const __bf16* __restrict__ io,
    __bf16* __restrict__ pj)
{
  int idx = xcd_swizzle(blockIdx.x, gridDim.x);
  const int chunk = idx & (XCH - 1); idx >>= 1;
  const int ys = idx % HS; idx /= HS;
  const int sidx = idx & 3;
  const int b = idx >> 2;
  const int sy = sidx >> 1, sx = sidx & 1;
  const int y = 2 * ys + sy;
  const int t = threadIdx.x;
  const int w = t >> 6;

  float wreg[3][9], ubias[3], gg[3], gb[3];
#pragma unroll
  for (int i = 0; i < 3; ++i) {
    const int c = t + i * 256;
    ubias[i] = upb[c * 4 + sidx];
    gg[i] = g[c];
    gb[i] = bb[c];
#pragma unroll
    for (int tap = 0; tap < 9; ++tap) {
      const int yy = ys - 1 + tap / 3;
      const float f = (yy >= 0 && yy < HS) ? 1.f : 0.f;   // fold row-OOB into weight
      wreg[i][tap] = upt[(sidx * 9 + tap) * DIM + c] * f;  // coalesced
    }
  }

  __shared__ __bf16 vals_lds[14][DIM];   // 21,504 B
  __shared__ float s1[14][4], s2[14][4];
  const int xs0 = chunk * 14;

  // clamped row indices (row-OOB contributes 0 via zeroed weights)
  const int y0 = max(ys - 1, 0), y1 = ys, y2 = min(ys + 1, HS - 1);
  const __bf16* vb0 = kv + ((size_t)(b * NS + y0 * WSS)) * (2 * DIM) + DIM + t;
  const __bf16* vb1 = kv + ((size_t)(b * NS + y1 * WSS)) * (2 * DIM) + DIM + t;
  const __bf16* vb2 = kv + ((size_t)(b * NS + y2 * WSS)) * (2 * DIM) + DIM + t;

  // unconditional clamped column load, col-OOB masked by multiply
  auto ldcol = [&](int ch, int p, float* dst) {
    const float m = (p >= 0 && p < WSS) ? 1.f : 0.f;
    const int xx = min(max(p, 0), WSS - 1);
    const size_t off = (size_t)xx * (2 * DIM) + ch * 256;
    dst[0] = m * (float)vb0[off];
    dst[1] = m * (float)vb1[off];
    dst[2] = m * (float)vb2[off];
  };

  float c0[3][3], c1[3][3], c2[3][3], cn[3][3];
#pragma unroll
  for (int ch = 0; ch < 3; ++ch) {
    ldcol(ch, xs0 - 1, c0[ch]);
    ldcol(ch, xs0,     c1[ch]);
    ldcol(ch, xs0 + 1, c2[ch]);
  }

#pragma unroll
  for (int xi = 0; xi < 14; ++xi) {
    const int xs = xs0 + xi;
#pragma unroll
    for (int ch = 0; ch < 3; ++ch) ldcol(ch, xs + 2, cn[ch]);
    float lsum = 0.f, lsq = 0.f;
#pragma unroll
    for (int ch = 0; ch < 3; ++ch) {
      float acc = ubias[ch];
#pragma unroll
      for (int dy = 0; dy < 3; ++dy) {
        acc = fmaf(wreg[ch][dy * 3 + 0], c0[ch][dy], acc);
        acc = fmaf(wreg[ch][dy * 3 + 1], c1[ch][dy], acc);
        acc = fmaf(wreg[ch][dy * 3 + 2], c2[ch][dy], acc);
      }
      vals_lds[xi][t + ch * 256] = (__bf16)acc;
      lsum += acc;
      lsq = fmaf(acc, acc, lsq);
    }
#pragma unroll
    for (int off = 32; off > 0; off >>= 1) {
      lsum += __shfl_xor(lsum, off);
      lsq  += __shfl_xor(lsq, off);
    }
    if ((t & 63) == 0) { s1[xi][w] = lsum; s2[xi][w] = lsq; }
#pragma unroll
    for (int ch = 0; ch < 3; ++ch)
#pragma unroll
      for (int dy = 0; dy < 3; ++dy) {
        c0[ch][dy] = c1[ch][dy];
        c1[ch][dy] = c2[ch][dy];
        c2[ch][dy] = cn[ch][dy];
      }
  }
  __syncthreads();   // ONE barrier: all conv values + partials in LDS

#pragma unroll
  for (int xi = 0; xi < 14; ++xi) {
    const float S  = s1[xi][0] + s1[xi][1] + s1[xi][2] + s1[xi][3];
    const float SQ = s2[xi][0] + s2[xi][1] + s2[xi][2] + s2[xi][3];
    const float mean = S * (1.f / 768.f);
    const float var  = SQ * (1.f / 768.f) - mean * mean;
    const float rstd = rsqrtf(var + 1e-6f);
    const int x = 2 * (xs0 + xi) + sx;
    const size_t row = (size_t)b * NQ + y * WW + x;
#pragma unroll
    for (int ch = 0; ch < 3; ++ch) {
      const int c = t + ch * 256;
      pj[row * DIM + c] =
          (__bf16)((float)io[row * DIM + c] +
                   ((float)vals_lds[xi][c] - mean) * rstd * gg[ch] + gb[ch]);
    }
  }
}

// =============================================================================
extern "C" void kernel_launch(void* const* d_in, const int* in_sizes, int n_in,
                              void* d_out, int out_size, void* d_ws, size_t ws_size,
                              hipStream_t stream)
{
  const float* x      = (const float*)d_in[0];
  const float* q_w    = (const float*)d_in[1];
  const float* q_b    = (const float*)d_in[2];
  const float* kv_w   = (const float*)d_in[3];
  const float* kv_b   = (const float*)d_in[4];
  const float* sr_w   = (const float*)d_in[5];
  const float* sr_b   = (const float*)d_in[6];
  const float* srn_g  = (const float*)d_in[7];
  const float* srn_b  = (const float*)d_in[8];
  const float* up_w   = (const float*)d_in[9];
  const float* up_b   = (const float*)d_in[10];
  const float* upn_g  = (const float*)d_in[11];
  const float* upn_b  = (const float*)d_in[12];
  const float* proj_w = (const float*)d_in[13];
  const float* proj_b = (const float*)d_in[14];
  const float* pq_w   = (const float*)d_in[15];
  const float* pk_w   = (const float*)d_in[16];
  const float* pv_w   = (const float*)d_in[17];
  const float* nq_g   = (const float*)d_in[18];
  const float* nq_b   = (const float*)d_in[19];
  const float* nk_g   = (const float*)d_in[20];
  const float* nk_b   = (const float*)d_in[21];
  const float* nv_g   = (const float*)d_in[22];
  const float* nv_b   = (const float*)d_in[23];

  const int B = in_sizes[0] / (NQ * DIM);   // 8
  const int M1 = B * NQ;                    // 25088
  const int M2 = B * NS;                    // 6272

  // workspace layout (bytes)
  char* p = (char*)d_ws;
  __bf16* xb    = (__bf16*)p;  p += (size_t)M1 * DIM * 2;        // x bf16; reused as pjin
  float*  qproj = (float*)p;   p += (size_t)M1 * DIM * 4;        // qp bf16 / attnout bf16
  __bf16* qf    = (__bf16*)p;  p += (size_t)M1 * DIM * 2;        // pooled+LN q (bf16)
  __bf16* xsln  = (__bf16*)p;  p += (size_t)M2 * DIM * 2;        // sr+LN out (bf16)
  __bf16* kvb   = (__bf16*)p;  p += (size_t)M2 * 2 * DIM * 2;    // kv-proj out (bf16)
  __bf16* kpb   = (__bf16*)p;  p += (size_t)B * NHD * NKP * HD * 2;   // pooled k, swizzled
  __bf16* vtb   = (__bf16*)p;  p += (size_t)B * NHD * HD * VSTR * 2;  // pooled v, transposed+swizzled
  __bf16* wqt   = (__bf16*)p;  p += (size_t)DIM * DIM * 2;       // q_w^T bf16 [N][K]
  __bf16* wkvt  = (__bf16*)p;  p += (size_t)DIM * 2 * DIM * 2;   // kv_w^T bf16
  __bf16* wpjt  = (__bf16*)p;  p += (size_t)DIM * DIM * 2;       // proj_w^T bf16
  float*  upt   = (float*)p;   p += (size_t)4 * 9 * DIM * 4;     // up_w transposed [sidx][tap][c]
  float*  srt   = (float*)p;   p += (size_t)9 * DIM * 4;         // sr_w transposed [tap][c]
  __bf16* qp      = (__bf16*)qproj;  // bf16 permuted q-proj (dead before attnout live)
  __bf16* attnout = (__bf16*)qproj;  // bf16 attention output (after qp dead)
  __bf16* pjin    = xb;

  dim3 blk(256);

  // 0. casts / weight transposes (merged: 3 dispatches)
  cast_bf16_kernel<<<2048, blk, 0, stream>>>(x, xb, (long)M1 * DIM / 4);
  wt3_cast_kernel<<<dim3(48, 24, 3), blk, 0, stream>>>(
      q_w, kv_w, proj_w, wqt, wkvt, wpjt);
  misc_tr_kernel<<<(5 * 9 * DIM + 255) / 256, blk, 0, stream>>>(
      up_w, upt, sr_w, srt);

  // 1. q projection (bf16 MFMA, triple-buf counted-vmcnt) -> qp bf16 permuted
  gemm_mfma_kernel<1><<<(M1 / 128) * (DIM / 128), blk, 0, stream>>>(
      xb, wqt, q_b, nullptr, qp, M1, DIM, DIM);

  // 2. pool_q conv + LN(64) -> bf16 (sliding-window, unconditional loads)
  pool_q_ln_kernel<<<B * NHD * HH, blk, 0, stream>>>(
      qp, pq_w, nq_g, nq_b, qf);

  // 3. spatial reduction conv + LN(768) -> bf16 (unconditional loads)
  sr_ln_kernel<<<B * NS, blk, 0, stream>>>(
      xb, srt, sr_b, srn_g, srn_b, xsln);

  // 4. kv projection (bf16 MFMA) -> bf16 row-major
  gemm_mfma_kernel<2><<<(M2 / 128) * (2 * DIM / 128), blk, 0, stream>>>(
      xsln, wkvt, kv_b, nullptr, kvb, M2, 2 * DIM, DIM);

  // 5. pool k (swizzled [bh][224][64]) and v (transposed+swizzled [bh][64][256])
  pool_kv_ln_kernel<<<dim3((B * NHD * NKP) / 4, 2), blk, 0, stream>>>(
      kvb, pk_w, pv_w, nk_g, nk_b, nv_g, nv_b, kpb, vtb);

  // 6. MFMA attention core -> attnout (bf16; 32KB LDS, P in registers)
  attn_mfma_kernel<<<dim3(NQ / 64, B * NHD), blk, 0, stream>>>(
      qf, kpb, vtb, attnout);

  // 7. identity path + add -> bf16 proj input (reuses xb region)
  idn_add_ln_kernel<<<B * 4 * HS * XCH, blk, 0, stream>>>(
      kvb, upt, up_b, upn_g, upn_b, attnout, pjin);

  // 8. output projection (bf16 MFMA) -> d_out (f32)
  gemm_mfma_kernel<0><<<(M1 / 128) * (DIM / 128), blk, 0, stream>>>(
      pjin, wpjt, proj_b, (float*)d_out, nullptr, M1, DIM, DIM);
}